// Round 1
// baseline (211.215 us; speedup 1.0000x reference)
//
#include <hip/hip_runtime.h>
#include <hip/hip_bf16.h>
#include <stdint.h>

// Problem constants
#define BATCH 4
#define SEQ   1024
#define EMB   1024
#define NHEAD 16
#define HDIM  64
#define MTOT  (BATCH*SEQ)          // 4096 rows
#define MELEM (MTOT*EMB)           // 4,194,304 elements per [B,S,E] tensor

typedef __attribute__((ext_vector_type(8))) short short8;
typedef __attribute__((ext_vector_type(4))) float f32x4;
typedef __attribute__((ext_vector_type(4))) unsigned short us4;

// fast f32->bf16: round-half-up via integer add (inputs finite, no NaN).
static __device__ __forceinline__ unsigned short f2bf_fast(float f) {
  unsigned u = __builtin_bit_cast(unsigned, f);
  return (unsigned short)((u + 0x8000u) >> 16);
}

// async global->LDS, 16B per lane. lds ptr must be WAVE-UNIFORM base;
// HW scatters lane i to base + i*16. (m97 recipe)
static __device__ __forceinline__ void cp16(const void* g, const void* lds_uniform) {
  __builtin_amdgcn_global_load_lds(
      (const __attribute__((address_space(1))) unsigned int*)(uintptr_t)g,
      (__attribute__((address_space(3))) unsigned int*)(unsigned int)(uintptr_t)lds_uniform,
      16, 0, 0);
}

// ---------------------------------------------------------------- convert f32 -> bf16 (Re & Im fused)
__global__ __launch_bounds__(256) void cvt_bf16(const float* __restrict__ in0,
                                                const float* __restrict__ in1,
                                                short* __restrict__ out0,
                                                short* __restrict__ out1) {
  const float* in  = blockIdx.y ? in1  : in0;
  short*       out = blockIdx.y ? out1 : out0;
  int i = blockIdx.x * 256 + threadIdx.x;   // each thread: 4 elements
  float4 f = ((const float4*)in)[i];
  unsigned r0 = ((unsigned)f2bf_fast(f.y) << 16) | f2bf_fast(f.x);
  unsigned r1 = ((unsigned)f2bf_fast(f.w) << 16) | f2bf_fast(f.z);
  ((uint2*)out)[i] = make_uint2(r0, r1);
}

// ---------------------------------------------------- transpose+convert W[k][n] -> Wt[n][k] bf16 (x4 fused)
__global__ __launch_bounds__(256) void wtrans(const float* __restrict__ W0,
                                              const float* __restrict__ W1,
                                              const float* __restrict__ W2,
                                              const float* __restrict__ W3,
                                              short* __restrict__ WtBase) {
  const int z = blockIdx.z;
  const float* W = (z == 0) ? W0 : (z == 1) ? W1 : (z == 2) ? W2 : W3;
  short* Wt = WtBase + (size_t)z * EMB * EMB;
  __shared__ short tile[32][33];
  int nT = blockIdx.x * 32, kT = blockIdx.y * 32;
  int tx = threadIdx.x, ty = threadIdx.y;
  #pragma unroll
  for (int i = 0; i < 4; ++i)
    tile[ty + 8*i][tx] = (short)f2bf_fast(W[(size_t)(kT + ty + 8*i) * EMB + nT + tx]);
  __syncthreads();
  #pragma unroll
  for (int i = 0; i < 4; ++i)
    Wt[(size_t)(nT + ty + 8*i) * EMB + kT + tx] = tile[tx][ty + 8*i];
}

// ---------------------------------------------------------------- fused QKV GEMM, 128x128 tiles (m97 structure)
// N fused to 3072 (Wt holds Wq^T|Wk^T|Wv^T contiguous). grid (24,32) = 768 blocks = 3/CU.
// Each wave: 64x64 output (acc[4][4]); per k-step one B-frag read feeds 4 MFMAs.
__global__ __launch_bounds__(256) void gemm_qkv(const short* __restrict__ A,
                                                const short* __restrict__ Wt,
                                                const float* __restrict__ bq,
                                                const float* __restrict__ bk,
                                                const float* __restrict__ bv,
                                                const float* __restrict__ pos,
                                                short* __restrict__ QKbase,
                                                short* __restrict__ vtOut) {
  const int m0 = blockIdx.y * 128, n0 = blockIdx.x * 128;
  const int z = n0 >> 10;                       // 0=Q 1=K 2=V (128-tile never crosses: 1024%128==0)
  const float* bias = (z == 0) ? bq : (z == 1 ? bk : bv);

  __shared__ __align__(16) short As[128 * 64];  // 16 KB
  __shared__ __align__(16) short Bs[128 * 64];  // 16 KB

  const int t = threadIdx.x;
  const int lane = t & 63, w = t >> 6;
  const int wm = w >> 1, wn = w & 1;            // wave tile 64m x 64n
  const int quad = lane >> 4, l16 = lane & 15;
  const int lrow8 = lane >> 3, lchunk = lane & 7;
  const int gch = lchunk ^ lrow8;               // swizzled source chunk
  const int sw7 = l16 & 7;

  const short* Arow = A  + (size_t)(m0 + w * 32 + lrow8) * EMB + gch * 8;
  const short* Brow = Wt + (size_t)(n0 + w * 32 + lrow8) * EMB + gch * 8;

  f32x4 acc[4][4] = {};

  for (int k0 = 0; k0 < EMB; k0 += 64) {
    #pragma unroll
    for (int s = 0; s < 4; ++s)
      cp16(Arow + (size_t)(s * 8) * EMB + k0, &As[(w * 32 + s * 8) * 64]);
    #pragma unroll
    for (int s = 0; s < 4; ++s)
      cp16(Brow + (size_t)(s * 8) * EMB + k0, &Bs[(w * 32 + s * 8) * 64]);
    __syncthreads();
    #pragma unroll
    for (int ks = 0; ks < 2; ++ks) {
      const int chv = ((ks << 2) + quad) ^ sw7;
      short8 af[4], bfr[4];
      #pragma unroll
      for (int i = 0; i < 4; ++i)
        af[i] = *(const short8*)&As[(wm * 64 + i * 16 + l16) * 64 + chv * 8];
      #pragma unroll
      for (int j = 0; j < 4; ++j)
        bfr[j] = *(const short8*)&Bs[(wn * 64 + j * 16 + l16) * 64 + chv * 8];
      #pragma unroll
      for (int i = 0; i < 4; ++i)
        #pragma unroll
        for (int j = 0; j < 4; ++j)
          acc[i][j] = __builtin_amdgcn_mfma_f32_16x16x32_bf16(af[i], bfr[j], acc[i][j], 0, 0, 0);
    }
    __syncthreads();
  }

  // epilogue: C row = quad*4+r, col = l16
  #pragma unroll
  for (int i = 0; i < 4; ++i) {
    int mbase = m0 + wm * 64 + i * 16 + quad * 4;
    #pragma unroll
    for (int j = 0; j < 4; ++j) {
      int n = n0 + wn * 64 + j * 16 + l16;
      int nl = n & 1023;
      float bn = bias[nl];
      int d = nl & (HDIM - 1);
      if (z == 2) {
        // write V transposed: [b,h,d,s] so attn stages Vt rows contiguously
        int bh = (mbase >> 10) * NHEAD + (nl >> 6);
        int s = mbase & (SEQ - 1);
        us4 pk;
        #pragma unroll
        for (int r = 0; r < 4; ++r) {
          float v = acc[i][j][r] + bn + pos[(size_t)(mbase + r) * HDIM + d];
          pk[r] = f2bf_fast(v);
        }
        *(us4*)&vtOut[((size_t)bh * HDIM + d) * SEQ + s] = pk;
      } else {
        #pragma unroll
        for (int r = 0; r < 4; ++r) {
          int mm = mbase + r;
          float v = acc[i][j][r] + bn + pos[(size_t)mm * HDIM + d];
          QKbase[(size_t)z * MELEM + (size_t)mm * EMB + nl] = (short)f2bf_fast(v);
        }
      }
    }
  }
}

// ---------------------------------------------------------------- Wo GEMM: 128x64 tiles (2 blocks/CU)
// Same structure as the previous (verified) gemm_qkv: wave tile 64m x 32n, acc[4][2].
__global__ __launch_bounds__(256) void gemm_wo(const short* __restrict__ A,
                                               const short* __restrict__ Bt,
                                               const float* __restrict__ bias,
                                               float* __restrict__ out) {
  const int m0 = blockIdx.y * 128, n0 = blockIdx.x * 64;

  __shared__ __align__(16) short As[128 * 64];  // 16 KB
  __shared__ __align__(16) short Bs[64 * 64];   // 8 KB

  const int t = threadIdx.x;
  const int lane = t & 63, w = t >> 6;
  const int wm = w >> 1, wn = w & 1;            // wave tile: 64m x 32n
  const int quad = lane >> 4, l16 = lane & 15;
  const int lrow8 = lane >> 3, lchunk = lane & 7;
  const int gch = lchunk ^ lrow8;
  const int sw7 = l16 & 7;

  const short* Arow = A  + (size_t)(m0 + w * 32 + lrow8) * EMB + gch * 8;
  const short* Brow = Bt + (size_t)(n0 + w * 16 + lrow8) * EMB + gch * 8;

  f32x4 acc[4][2] = {};

  for (int k0 = 0; k0 < EMB; k0 += 64) {
    #pragma unroll
    for (int s = 0; s < 4; ++s)
      cp16(Arow + (size_t)(s * 8) * EMB + k0, &As[(w * 32 + s * 8) * 64]);
    #pragma unroll
    for (int s = 0; s < 2; ++s)
      cp16(Brow + (size_t)(s * 8) * EMB + k0, &Bs[(w * 16 + s * 8) * 64]);
    __syncthreads();
    #pragma unroll
    for (int ks = 0; ks < 2; ++ks) {
      const int chv = ((ks << 2) + quad) ^ sw7;
      short8 af[4], bfr[2];
      #pragma unroll
      for (int i = 0; i < 4; ++i)
        af[i] = *(const short8*)&As[(wm * 64 + i * 16 + l16) * 64 + chv * 8];
      #pragma unroll
      for (int j = 0; j < 2; ++j)
        bfr[j] = *(const short8*)&Bs[(wn * 32 + j * 16 + l16) * 64 + chv * 8];
      #pragma unroll
      for (int i = 0; i < 4; ++i)
        #pragma unroll
        for (int j = 0; j < 2; ++j)
          acc[i][j] = __builtin_amdgcn_mfma_f32_16x16x32_bf16(af[i], bfr[j], acc[i][j], 0, 0, 0);
    }
    __syncthreads();
  }

  #pragma unroll
  for (int i = 0; i < 4; ++i) {
    int mbase = m0 + wm * 64 + i * 16 + quad * 4;
    #pragma unroll
    for (int j = 0; j < 2; ++j) {
      int n = n0 + wn * 32 + j * 16 + l16;
      float bn = bias[n];
      #pragma unroll
      for (int r = 0; r < 4; ++r)
        out[(size_t)(mbase + r) * EMB + n] = acc[i][j][r] + bn;
    }
  }
}

// ---------------------------------------------------------------- flash attention, phase-pipelined
// No-max softmax (scores bounded). Staging for tile kt+1 is issued MID-tile:
//   QK(kt) -> barrier -> cp16 K/Im(kt+1) -> exp+PV(kt) -> barrier -> cp16 Vt(kt+1)
// Each __syncthreads drains the wave's own vmcnt, so K/Im(kt+1) commits at the END
// barrier (a full exp+PV phase after issue) and Vt(kt+1) at the next MID barrier
// (a full QK phase after issue).
//
// R8 change: each wave owns 32 q-rows (2 row-groups g=0,1), q-tile 128, grid.y 8.
// Every LDS B-fragment read (K/Im/Vt) now feeds TWO MFMAs -> LDS-pipe traffic per
// FLOP ~halved (the measured bottleneck: ~90k of 115k cycles were LDS issue/BW).
// K/Im/Vt staging is also amortized over 2x the q-rows (HBM fetch ~halves).
__global__ __launch_bounds__(256) void attn(const short* __restrict__ Qp,
                                            const short* __restrict__ Kp,
                                            const short* __restrict__ VtG,
                                            const short* __restrict__ Imb,
                                            short* __restrict__ attnA) {
  const int qb = blockIdx.y * 128;
  const int bh = blockIdx.x;
  const int b = bh >> 4, h = bh & 15;
  const int t = threadIdx.x, lane = t & 63, w = t >> 6;   // w: 0..3
  const int quad = lane >> 4, l16 = lane & 15;
  const int lrow8 = lane >> 3, lchunk = lane & 7;
  const int gch = lchunk ^ lrow8;
  const int sw7 = l16 & 7;

  __shared__ __align__(16) short tiles[3 * 64 * 64];   // K | Im | Vt  (24576 B)
  __shared__ __align__(16) short Pw[4 * 32 * 64];      // swizzled, wave-private, 16384 B

  // per-wave A-fragments for Q and Im (rows qb + w*32 + g*16 + l16)
  short8 aq[2][2], aim[2][2];
  #pragma unroll
  for (int g = 0; g < 2; ++g) {
    const int q = qb + w * 32 + g * 16 + l16;
    const size_t qoff = ((size_t)(b * SEQ + q)) * EMB + h * HDIM + quad * 8;
    aq[g][0]  = *(const short8*)&Qp [qoff];
    aq[g][1]  = *(const short8*)&Qp [qoff + 32];
    aim[g][0] = *(const short8*)&Imb[qoff];
    aim[g][1] = *(const short8*)&Imb[qoff + 32];
  }

  float lr[2][4] = {};                  // per-lane partial row sums
  f32x4 o[2][4] = {};

  const float SC = 0.03125f * 1.44269504089f;   // /sqrt(1024) * log2(e)
  const size_t kimBase = ((size_t)b * SEQ) * EMB + h * HDIM + gch * 8;
  const size_t vtBase  = ((size_t)bh * HDIM) * SEQ + gch * 8;

  // prologue: stage all of tile 0 (6 cp16 per wave = 24 total = 3 x 8 KB)
  #pragma unroll
  for (int s = 0; s < 6; ++s) {
    const int I = w * 6 + s;
    const int tz = I >> 3;
    const int row = ((I & 7) * 8) + lrow8;
    const short* g;
    if (tz == 0)      g = Kp  + kimBase + (size_t)row * EMB;
    else if (tz == 1) g = Imb + kimBase + (size_t)row * EMB;
    else              g = VtG + vtBase + (size_t)row * SEQ;
    cp16(g, &tiles[I * 512]);
  }
  __syncthreads();

  for (int kt = 0; kt < 16; ++kt) {
    const int kBaseN = (kt + 1) * 64;   // next tile base (unused when kt==15)

    // ---- QK phase: 32 q-rows x 64 k-cols per wave; one bk/bi read -> 2 MFMAs
    f32x4 sa[2][4] = {};
    #pragma unroll
    for (int c = 0; c < 4; ++c) {
      const int rowoff = (c * 16 + l16) * 64;
      #pragma unroll
      for (int st = 0; st < 2; ++st) {
        const int chv = (((st << 2) + quad) ^ sw7) * 8;
        short8 bk = *(const short8*)&tiles[rowoff + chv];
        short8 bi = *(const short8*)&tiles[4096 + rowoff + chv];
        #pragma unroll
        for (int g = 0; g < 2; ++g) {
          sa[g][c] = __builtin_amdgcn_mfma_f32_16x16x32_bf16(aq [g][st], bk, sa[g][c], 0, 0, 0);
          sa[g][c] = __builtin_amdgcn_mfma_f32_16x16x32_bf16(aim[g][st], bi, sa[g][c], 0, 0, 0);
        }
      }
    }

    __syncthreads();   // all waves done reading K/Im(kt); Vt(kt) committed (own-vmcnt drain)

    // ---- stage K/Im for kt+1 (4 cp16 per wave = 16 KB); commits at END barrier
    if (kt != 15) {
      #pragma unroll
      for (int s = 0; s < 4; ++s) {
        const int I = w * 4 + s;            // 0..15
        const int row = ((I & 7) * 8) + lrow8;
        const short* g = ((I >> 3) ? Imb : Kp) + kimBase + (size_t)(kBaseN + row) * EMB;
        cp16(g, &tiles[I * 512]);
      }
    }

    // ---- exp + C->A layout transform (wave-private Pw, XOR-swizzled, no barrier)
    short* pw = &Pw[w * 2048];
    #pragma unroll
    for (int g = 0; g < 2; ++g) {
      #pragma unroll
      for (int c = 0; c < 4; ++c) {
        #pragma unroll
        for (int r = 0; r < 4; ++r) {
          float p = __builtin_amdgcn_exp2f(sa[g][c][r] * SC);
          lr[g][r] += p;
          const int row = quad * 4 + r;
          const int sch = ((c * 2 + (l16 >> 3)) ^ (row & 7));
          pw[(g * 16 + row) * 64 + sch * 8 + (l16 & 7)] = (short)f2bf_fast(p);
        }
      }
    }
    short8 ap[2][2];
    #pragma unroll
    for (int g = 0; g < 2; ++g) {
      ap[g][0] = *(const short8*)&pw[(g * 16 + l16) * 64 + ((quad       ^ sw7) * 8)];
      ap[g][1] = *(const short8*)&pw[(g * 16 + l16) * 64 + (((4 + quad) ^ sw7) * 8)];
    }

    // ---- PV phase: reads Vt(kt); one bv2 read -> 2 MFMAs
    #pragma unroll
    for (int cd = 0; cd < 4; ++cd) {
      const int rowoff = 8192 + (cd * 16 + l16) * 64;
      #pragma unroll
      for (int st = 0; st < 2; ++st) {
        short8 bv2 = *(const short8*)&tiles[rowoff + (((st << 2) + quad) ^ sw7) * 8];
        #pragma unroll
        for (int g = 0; g < 2; ++g)
          o[g][cd] = __builtin_amdgcn_mfma_f32_16x16x32_bf16(ap[g][st], bv2, o[g][cd], 0, 0, 0);
      }
    }

    __syncthreads();   // all waves done reading Vt(kt); K/Im(kt+1) committed

    // ---- stage Vt for kt+1 (2 cp16 per wave = 8 KB); commits at next MID barrier
    if (kt != 15) {
      #pragma unroll
      for (int s = 0; s < 2; ++s) {
        const int I = 16 + w * 2 + s;       // 16..23
        const int row = ((I & 7) * 8) + lrow8;
        cp16(VtG + vtBase + (size_t)row * SEQ + kBaseN, &tiles[I * 512]);
      }
    }
  }

  // epilogue: reduce row sums over the 16 lanes holding each row, normalize, store
  #pragma unroll
  for (int g = 0; g < 2; ++g)
    #pragma unroll
    for (int r = 0; r < 4; ++r) {
      #pragma unroll
      for (int msk = 1; msk < 16; msk <<= 1) lr[g][r] += __shfl_xor(lr[g][r], msk);
    }
  #pragma unroll
  for (int g = 0; g < 2; ++g) {
    #pragma unroll
    for (int r = 0; r < 4; ++r) {
      int qq = qb + w * 32 + g * 16 + quad * 4 + r;
      float inv = 1.f / lr[g][r];
      size_t base = ((size_t)(b * SEQ + qq)) * EMB + h * HDIM;
      #pragma unroll
      for (int cd = 0; cd < 4; ++cd)
        attnA[base + cd * 16 + l16] = (short)f2bf_fast(o[g][cd][r] * inv);
    }
  }
}

// ---------------------------------------------------------------- launch
extern "C" void kernel_launch(void* const* d_in, const int* in_sizes, int n_in,
                              void* d_out, int out_size, void* d_ws, size_t ws_size,
                              hipStream_t stream) {
  const float* Re  = (const float*)d_in[0];
  const float* Im  = (const float*)d_in[1];
  const float* pos = (const float*)d_in[2];
  const float* Wq  = (const float*)d_in[3];
  const float* bq  = (const float*)d_in[4];
  const float* Wk  = (const float*)d_in[5];
  const float* bk  = (const float*)d_in[6];
  const float* Wv  = (const float*)d_in[7];
  const float* bv  = (const float*)d_in[8];
  const float* Wo  = (const float*)d_in[9];
  const float* bo  = (const float*)d_in[10];

  short* ws    = (short*)d_ws;
  short* Rebf  = ws;                         // 4M shorts
  short* Imbf  = ws + (size_t)MELEM;         // 4M
  short* Wt    = ws + (size_t)2 * MELEM;     // 4 x 1M (q,k,v,o)
  short* Qp    = ws + (size_t)3 * MELEM;     // Q,K projections + Vt: 3 x 4M
  short* Kp    = Qp + (size_t)MELEM;
  short* VtG   = Qp + (size_t)2 * MELEM;     // V transposed [b,h,d,s]
  short* attnA = ws + (size_t)6 * MELEM;     // 4M

  cvt_bf16<<<dim3(MELEM / 1024, 2), 256, 0, stream>>>(Re, Im, Rebf, Imbf);

  wtrans<<<dim3(32, 32, 4), dim3(32, 8), 0, stream>>>(Wq, Wk, Wv, Wo, Wt);

  // fused Q/K/V projection (+bias +P), bf16 out; V written transposed. N fused to 3072.
  gemm_qkv<<<dim3(3 * EMB / 128, MTOT / 128), 256, 0, stream>>>(
      Rebf, Wt, bq, bk, bv, pos, Qp, VtG);

  // flash attention (x = bh for XCD-local L2 reuse of K/Im/Vt), 128-row q-tiles
  attn<<<dim3(BATCH * NHEAD, SEQ / 128), 256, 0, stream>>>(
      Qp, Kp, VtG, Imbf, attnA);

  // output projection, f32 out, 128x64 tiles (2 blocks/CU)
  gemm_wo<<<dim3(EMB / 64, MTOT / 128), 256, 0, stream>>>(
      attnA, Wt + 3 * EMB * EMB, bo, (float*)d_out);
}

// Round 2
// 200.989 us; speedup vs baseline: 1.0509x; 1.0509x over previous
//
#include <hip/hip_runtime.h>
#include <hip/hip_bf16.h>
#include <stdint.h>

// Problem constants
#define BATCH 4
#define SEQ   1024
#define EMB   1024
#define NHEAD 16
#define HDIM  64
#define MTOT  (BATCH*SEQ)          // 4096 rows
#define MELEM (MTOT*EMB)           // 4,194,304 elements per [B,S,E] tensor

typedef __attribute__((ext_vector_type(8))) short short8;
typedef __attribute__((ext_vector_type(4))) float f32x4;
typedef __attribute__((ext_vector_type(4))) unsigned short us4;

// fast f32->bf16: round-half-up via integer add (inputs finite, no NaN).
static __device__ __forceinline__ unsigned short f2bf_fast(float f) {
  unsigned u = __builtin_bit_cast(unsigned, f);
  return (unsigned short)((u + 0x8000u) >> 16);
}

// async global->LDS, 16B per lane. lds ptr must be WAVE-UNIFORM base;
// HW scatters lane i to base + i*16. (m97 recipe)
static __device__ __forceinline__ void cp16(const void* g, const void* lds_uniform) {
  __builtin_amdgcn_global_load_lds(
      (const __attribute__((address_space(1))) unsigned int*)(uintptr_t)g,
      (__attribute__((address_space(3))) unsigned int*)(unsigned int)(uintptr_t)lds_uniform,
      16, 0, 0);
}

// ---------------------------------------------------------------- convert f32 -> bf16 (Re & Im fused)
__global__ __launch_bounds__(256) void cvt_bf16(const float* __restrict__ in0,
                                                const float* __restrict__ in1,
                                                short* __restrict__ out0,
                                                short* __restrict__ out1) {
  const float* in  = blockIdx.y ? in1  : in0;
  short*       out = blockIdx.y ? out1 : out0;
  int i = blockIdx.x * 256 + threadIdx.x;   // each thread: 4 elements
  float4 f = ((const float4*)in)[i];
  unsigned r0 = ((unsigned)f2bf_fast(f.y) << 16) | f2bf_fast(f.x);
  unsigned r1 = ((unsigned)f2bf_fast(f.w) << 16) | f2bf_fast(f.z);
  ((uint2*)out)[i] = make_uint2(r0, r1);
}

// ---------------------------------------------------- transpose+convert W[k][n] -> Wt[n][k] bf16 (x4 fused)
__global__ __launch_bounds__(256) void wtrans(const float* __restrict__ W0,
                                              const float* __restrict__ W1,
                                              const float* __restrict__ W2,
                                              const float* __restrict__ W3,
                                              short* __restrict__ WtBase) {
  const int z = blockIdx.z;
  const float* W = (z == 0) ? W0 : (z == 1) ? W1 : (z == 2) ? W2 : W3;
  short* Wt = WtBase + (size_t)z * EMB * EMB;
  __shared__ short tile[32][33];
  int nT = blockIdx.x * 32, kT = blockIdx.y * 32;
  int tx = threadIdx.x, ty = threadIdx.y;
  #pragma unroll
  for (int i = 0; i < 4; ++i)
    tile[ty + 8*i][tx] = (short)f2bf_fast(W[(size_t)(kT + ty + 8*i) * EMB + nT + tx]);
  __syncthreads();
  #pragma unroll
  for (int i = 0; i < 4; ++i)
    Wt[(size_t)(nT + ty + 8*i) * EMB + kT + tx] = tile[tx][ty + 8*i];
}

// ---------------------------------------------------------------- fused QKV GEMM, 128x64 tiles
// N fused to 3072 (Wt holds Wq^T|Wk^T|Wv^T contiguous). grid (48,32) = 1536 blocks = 6/CU.
// (R1 lesson: at K=1024 / 16 K-steps this kernel is latency/barrier-bound, not
// compute-bound — 6 blocks/CU of inter-block overlap beats the 128x128 m97 tile
// at 3/CU, which measured 51.5 us vs ~46 here.)
__global__ __launch_bounds__(256) void gemm_qkv(const short* __restrict__ A,
                                                const short* __restrict__ Wt,
                                                const float* __restrict__ bq,
                                                const float* __restrict__ bk,
                                                const float* __restrict__ bv,
                                                const float* __restrict__ pos,
                                                short* __restrict__ QKbase,
                                                short* __restrict__ vtOut) {
  const int m0 = blockIdx.y * 128, n0 = blockIdx.x * 64;
  const int z = n0 >> 10;                       // 0=Q 1=K 2=V (64-tile never crosses)
  const float* bias = (z == 0) ? bq : (z == 1 ? bk : bv);

  __shared__ __align__(16) short As[128 * 64];  // 16 KB
  __shared__ __align__(16) short Bs[64 * 64];   // 8 KB

  const int t = threadIdx.x;
  const int lane = t & 63, w = t >> 6;
  const int wm = w >> 1, wn = w & 1;            // wave tile 64m x 32n
  const int quad = lane >> 4, l16 = lane & 15;
  const int lrow8 = lane >> 3, lchunk = lane & 7;
  const int gch = lchunk ^ lrow8;               // swizzled source chunk
  const int sw7 = l16 & 7;

  const short* Arow = A  + (size_t)(m0 + w * 32 + lrow8) * EMB + gch * 8;
  const short* Brow = Wt + (size_t)(n0 + w * 16 + lrow8) * EMB + gch * 8;

  f32x4 acc[4][2] = {};

  for (int k0 = 0; k0 < EMB; k0 += 64) {
    #pragma unroll
    for (int s = 0; s < 4; ++s)
      cp16(Arow + (size_t)(s * 8) * EMB + k0, &As[(w * 32 + s * 8) * 64]);
    #pragma unroll
    for (int s = 0; s < 2; ++s)
      cp16(Brow + (size_t)(s * 8) * EMB + k0, &Bs[(w * 16 + s * 8) * 64]);
    __syncthreads();
    #pragma unroll
    for (int ks = 0; ks < 2; ++ks) {
      const int chv = ((ks << 2) + quad) ^ sw7;
      short8 af[4], bfr[2];
      #pragma unroll
      for (int i = 0; i < 4; ++i)
        af[i] = *(const short8*)&As[(wm * 64 + i * 16 + l16) * 64 + chv * 8];
      #pragma unroll
      for (int j = 0; j < 2; ++j)
        bfr[j] = *(const short8*)&Bs[(wn * 32 + j * 16 + l16) * 64 + chv * 8];
      #pragma unroll
      for (int i = 0; i < 4; ++i)
        #pragma unroll
        for (int j = 0; j < 2; ++j)
          acc[i][j] = __builtin_amdgcn_mfma_f32_16x16x32_bf16(af[i], bfr[j], acc[i][j], 0, 0, 0);
    }
    __syncthreads();
  }

  // epilogue: C row = quad*4+r, col = l16
  #pragma unroll
  for (int i = 0; i < 4; ++i) {
    int mbase = m0 + wm * 64 + i * 16 + quad * 4;
    #pragma unroll
    for (int j = 0; j < 2; ++j) {
      int n = n0 + wn * 32 + j * 16 + l16;
      int nl = n & 1023;
      float bn = bias[nl];
      int d = nl & (HDIM - 1);
      if (z == 2) {
        // write V transposed: [b,h,d,s] so attn stages Vt rows contiguously
        int bh = (mbase >> 10) * NHEAD + (nl >> 6);
        int s = mbase & (SEQ - 1);
        us4 pk;
        #pragma unroll
        for (int r = 0; r < 4; ++r) {
          float v = acc[i][j][r] + bn + pos[(size_t)(mbase + r) * HDIM + d];
          pk[r] = f2bf_fast(v);
        }
        *(us4*)&vtOut[((size_t)bh * HDIM + d) * SEQ + s] = pk;
      } else {
        #pragma unroll
        for (int r = 0; r < 4; ++r) {
          int mm = mbase + r;
          float v = acc[i][j][r] + bn + pos[(size_t)mm * HDIM + d];
          QKbase[(size_t)z * MELEM + (size_t)mm * EMB + nl] = (short)f2bf_fast(v);
        }
      }
    }
  }
}

// ---------------------------------------------------------------- Wo GEMM: 64x64 tiles (4 blocks/CU)
__global__ __launch_bounds__(256) void gemm_wo(const short* __restrict__ A,
                                               const short* __restrict__ Bt,
                                               const float* __restrict__ bias,
                                               float* __restrict__ out) {
  const int m0 = blockIdx.y * 64, n0 = blockIdx.x * 64;

  __shared__ __align__(16) short As[64 * 64];
  __shared__ __align__(16) short Bs[64 * 64];

  const int t = threadIdx.x;
  const int lane = t & 63, w = t >> 6;
  const int wm = w >> 1, wn = w & 1;          // wave tile: 32m x 32n
  const int quad = lane >> 4, l16 = lane & 15;
  const int lrow8 = lane >> 3, lchunk = lane & 7;
  const int gch = lchunk ^ lrow8;
  const int sw7 = l16 & 7;

  const short* Arow = A  + (size_t)(m0 + w * 16 + lrow8) * EMB + gch * 8;
  const short* Brow = Bt + (size_t)(n0 + w * 16 + lrow8) * EMB + gch * 8;

  f32x4 acc[2][2] = {};

  for (int k0 = 0; k0 < EMB; k0 += 64) {
    #pragma unroll
    for (int s = 0; s < 2; ++s) {
      cp16(Arow + (size_t)(s * 8) * EMB + k0, &As[(w * 16 + s * 8) * 64]);
      cp16(Brow + (size_t)(s * 8) * EMB + k0, &Bs[(w * 16 + s * 8) * 64]);
    }
    __syncthreads();
    #pragma unroll
    for (int ks = 0; ks < 2; ++ks) {
      const int chv = ((ks << 2) + quad) ^ sw7;
      short8 af[2], bfr[2];
      #pragma unroll
      for (int i = 0; i < 2; ++i)
        af[i] = *(const short8*)&As[(wm * 32 + i * 16 + l16) * 64 + chv * 8];
      #pragma unroll
      for (int j = 0; j < 2; ++j)
        bfr[j] = *(const short8*)&Bs[(wn * 32 + j * 16 + l16) * 64 + chv * 8];
      #pragma unroll
      for (int i = 0; i < 2; ++i)
        #pragma unroll
        for (int j = 0; j < 2; ++j)
          acc[i][j] = __builtin_amdgcn_mfma_f32_16x16x32_bf16(af[i], bfr[j], acc[i][j], 0, 0, 0);
    }
    __syncthreads();
  }

  #pragma unroll
  for (int i = 0; i < 2; ++i) {
    int mbase = m0 + wm * 32 + i * 16 + quad * 4;
    #pragma unroll
    for (int j = 0; j < 2; ++j) {
      int n = n0 + wn * 32 + j * 16 + l16;
      float bn = bias[n];
      #pragma unroll
      for (int r = 0; r < 4; ++r)
        out[(size_t)(mbase + r) * EMB + n] = acc[i][j][r] + bn;
    }
  }
}

// ---------------------------------------------------------------- flash attention, phase-pipelined
// No-max softmax (scores bounded). Staging for tile kt+1 is issued MID-tile:
//   QK(kt) -> barrier -> cp16 K/Im(kt+1) -> exp+PV(kt) -> barrier -> cp16 Vt(kt+1)
// Each __syncthreads drains the wave's own vmcnt, so K/Im(kt+1) commits at the END
// barrier (a full exp+PV phase after issue) and Vt(kt+1) at the next MID barrier
// (a full QK phase after issue).
//
// R8 change (kept from R1): each wave owns 32 q-rows (2 row-groups g=0,1), q-tile 128,
// grid.y 8. Every LDS B-fragment read (K/Im/Vt) feeds TWO MFMAs -> LDS-pipe traffic
// per FLOP ~halved; K/Im/Vt staging amortized over 2x the q-rows.
__global__ __launch_bounds__(256) void attn(const short* __restrict__ Qp,
                                            const short* __restrict__ Kp,
                                            const short* __restrict__ VtG,
                                            const short* __restrict__ Imb,
                                            short* __restrict__ attnA) {
  const int qb = blockIdx.y * 128;
  const int bh = blockIdx.x;
  const int b = bh >> 4, h = bh & 15;
  const int t = threadIdx.x, lane = t & 63, w = t >> 6;   // w: 0..3
  const int quad = lane >> 4, l16 = lane & 15;
  const int lrow8 = lane >> 3, lchunk = lane & 7;
  const int gch = lchunk ^ lrow8;
  const int sw7 = l16 & 7;

  __shared__ __align__(16) short tiles[3 * 64 * 64];   // K | Im | Vt  (24576 B)
  __shared__ __align__(16) short Pw[4 * 32 * 64];      // swizzled, wave-private, 16384 B

  // per-wave A-fragments for Q and Im (rows qb + w*32 + g*16 + l16)
  short8 aq[2][2], aim[2][2];
  #pragma unroll
  for (int g = 0; g < 2; ++g) {
    const int q = qb + w * 32 + g * 16 + l16;
    const size_t qoff = ((size_t)(b * SEQ + q)) * EMB + h * HDIM + quad * 8;
    aq[g][0]  = *(const short8*)&Qp [qoff];
    aq[g][1]  = *(const short8*)&Qp [qoff + 32];
    aim[g][0] = *(const short8*)&Imb[qoff];
    aim[g][1] = *(const short8*)&Imb[qoff + 32];
  }

  float lr[2][4] = {};                  // per-lane partial row sums
  f32x4 o[2][4] = {};

  const float SC = 0.03125f * 1.44269504089f;   // /sqrt(1024) * log2(e)
  const size_t kimBase = ((size_t)b * SEQ) * EMB + h * HDIM + gch * 8;
  const size_t vtBase  = ((size_t)bh * HDIM) * SEQ + gch * 8;

  // prologue: stage all of tile 0 (6 cp16 per wave = 24 total = 3 x 8 KB)
  #pragma unroll
  for (int s = 0; s < 6; ++s) {
    const int I = w * 6 + s;
    const int tz = I >> 3;
    const int row = ((I & 7) * 8) + lrow8;
    const short* g;
    if (tz == 0)      g = Kp  + kimBase + (size_t)row * EMB;
    else if (tz == 1) g = Imb + kimBase + (size_t)row * EMB;
    else              g = VtG + vtBase + (size_t)row * SEQ;
    cp16(g, &tiles[I * 512]);
  }
  __syncthreads();

  for (int kt = 0; kt < 16; ++kt) {
    const int kBaseN = (kt + 1) * 64;   // next tile base (unused when kt==15)

    // ---- QK phase: 32 q-rows x 64 k-cols per wave; one bk/bi read -> 2 MFMAs
    f32x4 sa[2][4] = {};
    #pragma unroll
    for (int c = 0; c < 4; ++c) {
      const int rowoff = (c * 16 + l16) * 64;
      #pragma unroll
      for (int st = 0; st < 2; ++st) {
        const int chv = (((st << 2) + quad) ^ sw7) * 8;
        short8 bk = *(const short8*)&tiles[rowoff + chv];
        short8 bi = *(const short8*)&tiles[4096 + rowoff + chv];
        #pragma unroll
        for (int g = 0; g < 2; ++g) {
          sa[g][c] = __builtin_amdgcn_mfma_f32_16x16x32_bf16(aq [g][st], bk, sa[g][c], 0, 0, 0);
          sa[g][c] = __builtin_amdgcn_mfma_f32_16x16x32_bf16(aim[g][st], bi, sa[g][c], 0, 0, 0);
        }
      }
    }

    __syncthreads();   // all waves done reading K/Im(kt); Vt(kt) committed (own-vmcnt drain)

    // ---- stage K/Im for kt+1 (4 cp16 per wave = 16 KB); commits at END barrier
    if (kt != 15) {
      #pragma unroll
      for (int s = 0; s < 4; ++s) {
        const int I = w * 4 + s;            // 0..15
        const int row = ((I & 7) * 8) + lrow8;
        const short* g = ((I >> 3) ? Imb : Kp) + kimBase + (size_t)(kBaseN + row) * EMB;
        cp16(g, &tiles[I * 512]);
      }
    }

    // ---- exp + C->A layout transform (wave-private Pw, XOR-swizzled, no barrier)
    short* pw = &Pw[w * 2048];
    #pragma unroll
    for (int g = 0; g < 2; ++g) {
      #pragma unroll
      for (int c = 0; c < 4; ++c) {
        #pragma unroll
        for (int r = 0; r < 4; ++r) {
          float p = __builtin_amdgcn_exp2f(sa[g][c][r] * SC);
          lr[g][r] += p;
          const int row = quad * 4 + r;
          const int sch = ((c * 2 + (l16 >> 3)) ^ (row & 7));
          pw[(g * 16 + row) * 64 + sch * 8 + (l16 & 7)] = (short)f2bf_fast(p);
        }
      }
    }
    short8 ap[2][2];
    #pragma unroll
    for (int g = 0; g < 2; ++g) {
      ap[g][0] = *(const short8*)&pw[(g * 16 + l16) * 64 + ((quad       ^ sw7) * 8)];
      ap[g][1] = *(const short8*)&pw[(g * 16 + l16) * 64 + (((4 + quad) ^ sw7) * 8)];
    }

    // ---- PV phase: reads Vt(kt); one bv2 read -> 2 MFMAs
    #pragma unroll
    for (int cd = 0; cd < 4; ++cd) {
      const int rowoff = 8192 + (cd * 16 + l16) * 64;
      #pragma unroll
      for (int st = 0; st < 2; ++st) {
        short8 bv2 = *(const short8*)&tiles[rowoff + (((st << 2) + quad) ^ sw7) * 8];
        #pragma unroll
        for (int g = 0; g < 2; ++g)
          o[g][cd] = __builtin_amdgcn_mfma_f32_16x16x32_bf16(ap[g][st], bv2, o[g][cd], 0, 0, 0);
      }
    }

    __syncthreads();   // all waves done reading Vt(kt); K/Im(kt+1) committed

    // ---- stage Vt for kt+1 (2 cp16 per wave = 8 KB); commits at next MID barrier
    if (kt != 15) {
      #pragma unroll
      for (int s = 0; s < 2; ++s) {
        const int I = 16 + w * 2 + s;       // 16..23
        const int row = ((I & 7) * 8) + lrow8;
        cp16(VtG + vtBase + (size_t)row * SEQ + kBaseN, &tiles[I * 512]);
      }
    }
  }

  // epilogue: reduce row sums over the 16 lanes holding each row, normalize, store
  #pragma unroll
  for (int g = 0; g < 2; ++g)
    #pragma unroll
    for (int r = 0; r < 4; ++r) {
      #pragma unroll
      for (int msk = 1; msk < 16; msk <<= 1) lr[g][r] += __shfl_xor(lr[g][r], msk);
    }
  #pragma unroll
  for (int g = 0; g < 2; ++g) {
    #pragma unroll
    for (int r = 0; r < 4; ++r) {
      int qq = qb + w * 32 + g * 16 + quad * 4 + r;
      float inv = 1.f / lr[g][r];
      size_t base = ((size_t)(b * SEQ + qq)) * EMB + h * HDIM;
      #pragma unroll
      for (int cd = 0; cd < 4; ++cd)
        attnA[base + cd * 16 + l16] = (short)f2bf_fast(o[g][cd][r] * inv);
    }
  }
}

// ---------------------------------------------------------------- launch
extern "C" void kernel_launch(void* const* d_in, const int* in_sizes, int n_in,
                              void* d_out, int out_size, void* d_ws, size_t ws_size,
                              hipStream_t stream) {
  const float* Re  = (const float*)d_in[0];
  const float* Im  = (const float*)d_in[1];
  const float* pos = (const float*)d_in[2];
  const float* Wq  = (const float*)d_in[3];
  const float* bq  = (const float*)d_in[4];
  const float* Wk  = (const float*)d_in[5];
  const float* bk  = (const float*)d_in[6];
  const float* Wv  = (const float*)d_in[7];
  const float* bv  = (const float*)d_in[8];
  const float* Wo  = (const float*)d_in[9];
  const float* bo  = (const float*)d_in[10];

  short* ws    = (short*)d_ws;
  short* Rebf  = ws;                         // 4M shorts
  short* Imbf  = ws + (size_t)MELEM;         // 4M
  short* Wt    = ws + (size_t)2 * MELEM;     // 4 x 1M (q,k,v,o)
  short* Qp    = ws + (size_t)3 * MELEM;     // Q,K projections + Vt: 3 x 4M
  short* Kp    = Qp + (size_t)MELEM;
  short* VtG   = Qp + (size_t)2 * MELEM;     // V transposed [b,h,d,s]
  short* attnA = ws + (size_t)6 * MELEM;     // 4M

  cvt_bf16<<<dim3(MELEM / 1024, 2), 256, 0, stream>>>(Re, Im, Rebf, Imbf);

  wtrans<<<dim3(32, 32, 4), dim3(32, 8), 0, stream>>>(Wq, Wk, Wv, Wo, Wt);

  // fused Q/K/V projection (+bias +P), bf16 out; V written transposed. N fused to 3072.
  gemm_qkv<<<dim3(3 * EMB / 64, MTOT / 128), 256, 0, stream>>>(
      Rebf, Wt, bq, bk, bv, pos, Qp, VtG);

  // flash attention (x = bh for XCD-local L2 reuse of K/Im/Vt), 128-row q-tiles
  attn<<<dim3(BATCH * NHEAD, SEQ / 128), 256, 0, stream>>>(
      Qp, Kp, VtG, Imbf, attnA);

  // output projection, f32 out, 64x64 tiles for 4 blocks/CU
  gemm_wo<<<dim3(EMB / 64, MTOT / 64), 256, 0, stream>>>(
      attnA, Wt + 3 * EMB * EMB, bo, (float*)d_out);
}

// Round 3
// 193.745 us; speedup vs baseline: 1.0902x; 1.0374x over previous
//
#include <hip/hip_runtime.h>
#include <hip/hip_bf16.h>
#include <stdint.h>

// Problem constants
#define BATCH 4
#define SEQ   1024
#define EMB   1024
#define NHEAD 16
#define HDIM  64
#define MTOT  (BATCH*SEQ)          // 4096 rows
#define MELEM (MTOT*EMB)           // 4,194,304 elements per [B,S,E] tensor

typedef __attribute__((ext_vector_type(8))) short short8;
typedef __attribute__((ext_vector_type(4))) float f32x4;
typedef __attribute__((ext_vector_type(16))) float f32x16;
typedef __attribute__((ext_vector_type(4))) unsigned short us4;
typedef __attribute__((ext_vector_type(2))) unsigned int u32x2;
typedef __attribute__((ext_vector_type(4))) unsigned int u32x4;

// fast f32->bf16: round-half-up via integer add (inputs finite, no NaN).
static __device__ __forceinline__ unsigned short f2bf_fast(float f) {
  unsigned u = __builtin_bit_cast(unsigned, f);
  return (unsigned short)((u + 0x8000u) >> 16);
}

// packed f32x2 -> bf16x2 (RNE), no builtin on gfx950 (T12/m240) -> inline asm
static __device__ __forceinline__ unsigned cvt_pk_bf16(float lo, float hi) {
  unsigned r;
  asm("v_cvt_pk_bf16_f32 %0, %1, %2" : "=v"(r) : "v"(lo), "v"(hi));
  return r;
}

// async global->LDS, 16B per lane. lds ptr must be WAVE-UNIFORM base;
// HW scatters lane i to base + i*16. (m97 recipe)
static __device__ __forceinline__ void cp16(const void* g, const void* lds_uniform) {
  __builtin_amdgcn_global_load_lds(
      (const __attribute__((address_space(1))) unsigned int*)(uintptr_t)g,
      (__attribute__((address_space(3))) unsigned int*)(unsigned int)(uintptr_t)lds_uniform,
      16, 0, 0);
}

// ---------------------------------------------------------------- convert f32 -> bf16 (Re & Im fused)
__global__ __launch_bounds__(256) void cvt_bf16(const float* __restrict__ in0,
                                                const float* __restrict__ in1,
                                                short* __restrict__ out0,
                                                short* __restrict__ out1) {
  const float* in  = blockIdx.y ? in1  : in0;
  short*       out = blockIdx.y ? out1 : out0;
  int i = blockIdx.x * 256 + threadIdx.x;   // each thread: 4 elements
  float4 f = ((const float4*)in)[i];
  unsigned r0 = ((unsigned)f2bf_fast(f.y) << 16) | f2bf_fast(f.x);
  unsigned r1 = ((unsigned)f2bf_fast(f.w) << 16) | f2bf_fast(f.z);
  ((uint2*)out)[i] = make_uint2(r0, r1);
}

// ---------------------------------------------------- transpose+convert W[k][n] -> Wt[n][k] bf16 (x4 fused)
__global__ __launch_bounds__(256) void wtrans(const float* __restrict__ W0,
                                              const float* __restrict__ W1,
                                              const float* __restrict__ W2,
                                              const float* __restrict__ W3,
                                              short* __restrict__ WtBase) {
  const int z = blockIdx.z;
  const float* W = (z == 0) ? W0 : (z == 1) ? W1 : (z == 2) ? W2 : W3;
  short* Wt = WtBase + (size_t)z * EMB * EMB;
  __shared__ short tile[32][33];
  int nT = blockIdx.x * 32, kT = blockIdx.y * 32;
  int tx = threadIdx.x, ty = threadIdx.y;
  #pragma unroll
  for (int i = 0; i < 4; ++i)
    tile[ty + 8*i][tx] = (short)f2bf_fast(W[(size_t)(kT + ty + 8*i) * EMB + nT + tx]);
  __syncthreads();
  #pragma unroll
  for (int i = 0; i < 4; ++i)
    Wt[(size_t)(nT + ty + 8*i) * EMB + kT + tx] = tile[tx][ty + 8*i];
}

// ---------------------------------------------------------------- fused QKV GEMM, 128x64 tiles
// N fused to 3072 (Wt holds Wq^T|Wk^T|Wv^T contiguous). grid (48,32) = 1536 blocks = 6/CU.
// (R1 lesson: at K=1024 this is latency/barrier-bound; 6 blocks/CU of inter-block
// overlap beats the 128x128 m97 tile at 3/CU, 46 vs 51.5 us.)
__global__ __launch_bounds__(256) void gemm_qkv(const short* __restrict__ A,
                                                const short* __restrict__ Wt,
                                                const float* __restrict__ bq,
                                                const float* __restrict__ bk,
                                                const float* __restrict__ bv,
                                                const float* __restrict__ pos,
                                                short* __restrict__ QKbase,
                                                short* __restrict__ vtOut) {
  const int m0 = blockIdx.y * 128, n0 = blockIdx.x * 64;
  const int z = n0 >> 10;                       // 0=Q 1=K 2=V (64-tile never crosses)
  const float* bias = (z == 0) ? bq : (z == 1 ? bk : bv);

  __shared__ __align__(16) short As[128 * 64];  // 16 KB
  __shared__ __align__(16) short Bs[64 * 64];   // 8 KB

  const int t = threadIdx.x;
  const int lane = t & 63, w = t >> 6;
  const int wm = w >> 1, wn = w & 1;            // wave tile 64m x 32n
  const int quad = lane >> 4, l16 = lane & 15;
  const int lrow8 = lane >> 3, lchunk = lane & 7;
  const int gch = lchunk ^ lrow8;               // swizzled source chunk
  const int sw7 = l16 & 7;

  const short* Arow = A  + (size_t)(m0 + w * 32 + lrow8) * EMB + gch * 8;
  const short* Brow = Wt + (size_t)(n0 + w * 16 + lrow8) * EMB + gch * 8;

  f32x4 acc[4][2] = {};

  for (int k0 = 0; k0 < EMB; k0 += 64) {
    #pragma unroll
    for (int s = 0; s < 4; ++s)
      cp16(Arow + (size_t)(s * 8) * EMB + k0, &As[(w * 32 + s * 8) * 64]);
    #pragma unroll
    for (int s = 0; s < 2; ++s)
      cp16(Brow + (size_t)(s * 8) * EMB + k0, &Bs[(w * 16 + s * 8) * 64]);
    __syncthreads();
    #pragma unroll
    for (int ks = 0; ks < 2; ++ks) {
      const int chv = ((ks << 2) + quad) ^ sw7;
      short8 af[4], bfr[2];
      #pragma unroll
      for (int i = 0; i < 4; ++i)
        af[i] = *(const short8*)&As[(wm * 64 + i * 16 + l16) * 64 + chv * 8];
      #pragma unroll
      for (int j = 0; j < 2; ++j)
        bfr[j] = *(const short8*)&Bs[(wn * 32 + j * 16 + l16) * 64 + chv * 8];
      #pragma unroll
      for (int i = 0; i < 4; ++i)
        #pragma unroll
        for (int j = 0; j < 2; ++j)
          acc[i][j] = __builtin_amdgcn_mfma_f32_16x16x32_bf16(af[i], bfr[j], acc[i][j], 0, 0, 0);
    }
    __syncthreads();
  }

  // epilogue: C row = quad*4+r, col = l16
  #pragma unroll
  for (int i = 0; i < 4; ++i) {
    int mbase = m0 + wm * 64 + i * 16 + quad * 4;
    #pragma unroll
    for (int j = 0; j < 2; ++j) {
      int n = n0 + wn * 32 + j * 16 + l16;
      int nl = n & 1023;
      float bn = bias[nl];
      int d = nl & (HDIM - 1);
      if (z == 2) {
        // write V transposed: [b,h,d,s] so attn stages Vt rows contiguously
        int bh = (mbase >> 10) * NHEAD + (nl >> 6);
        int s = mbase & (SEQ - 1);
        us4 pk;
        #pragma unroll
        for (int r = 0; r < 4; ++r) {
          float v = acc[i][j][r] + bn + pos[(size_t)(mbase + r) * HDIM + d];
          pk[r] = f2bf_fast(v);
        }
        *(us4*)&vtOut[((size_t)bh * HDIM + d) * SEQ + s] = pk;
      } else {
        #pragma unroll
        for (int r = 0; r < 4; ++r) {
          int mm = mbase + r;
          float v = acc[i][j][r] + bn + pos[(size_t)mm * HDIM + d];
          QKbase[(size_t)z * MELEM + (size_t)mm * EMB + nl] = (short)f2bf_fast(v);
        }
      }
    }
  }
}

// ---------------------------------------------------------------- Wo GEMM: 64x64 tiles (4 blocks/CU)
__global__ __launch_bounds__(256) void gemm_wo(const short* __restrict__ A,
                                               const short* __restrict__ Bt,
                                               const float* __restrict__ bias,
                                               float* __restrict__ out) {
  const int m0 = blockIdx.y * 64, n0 = blockIdx.x * 64;

  __shared__ __align__(16) short As[64 * 64];
  __shared__ __align__(16) short Bs[64 * 64];

  const int t = threadIdx.x;
  const int lane = t & 63, w = t >> 6;
  const int wm = w >> 1, wn = w & 1;          // wave tile: 32m x 32n
  const int quad = lane >> 4, l16 = lane & 15;
  const int lrow8 = lane >> 3, lchunk = lane & 7;
  const int gch = lchunk ^ lrow8;
  const int sw7 = l16 & 7;

  const short* Arow = A  + (size_t)(m0 + w * 16 + lrow8) * EMB + gch * 8;
  const short* Brow = Bt + (size_t)(n0 + w * 16 + lrow8) * EMB + gch * 8;

  f32x4 acc[2][2] = {};

  for (int k0 = 0; k0 < EMB; k0 += 64) {
    #pragma unroll
    for (int s = 0; s < 2; ++s) {
      cp16(Arow + (size_t)(s * 8) * EMB + k0, &As[(w * 16 + s * 8) * 64]);
      cp16(Brow + (size_t)(s * 8) * EMB + k0, &Bs[(w * 16 + s * 8) * 64]);
    }
    __syncthreads();
    #pragma unroll
    for (int ks = 0; ks < 2; ++ks) {
      const int chv = ((ks << 2) + quad) ^ sw7;
      short8 af[2], bfr[2];
      #pragma unroll
      for (int i = 0; i < 2; ++i)
        af[i] = *(const short8*)&As[(wm * 32 + i * 16 + l16) * 64 + chv * 8];
      #pragma unroll
      for (int j = 0; j < 2; ++j)
        bfr[j] = *(const short8*)&Bs[(wn * 32 + j * 16 + l16) * 64 + chv * 8];
      #pragma unroll
      for (int i = 0; i < 2; ++i)
        #pragma unroll
        for (int j = 0; j < 2; ++j)
          acc[i][j] = __builtin_amdgcn_mfma_f32_16x16x32_bf16(af[i], bfr[j], acc[i][j], 0, 0, 0);
    }
    __syncthreads();
  }

  #pragma unroll
  for (int i = 0; i < 2; ++i) {
    int mbase = m0 + wm * 32 + i * 16 + quad * 4;
    #pragma unroll
    for (int j = 0; j < 2; ++j) {
      int n = n0 + wn * 32 + j * 16 + l16;
      float bn = bias[n];
      #pragma unroll
      for (int r = 0; r < 4; ++r)
        out[(size_t)(mbase + r) * EMB + n] = acc[i][j][r] + bn;
    }
  }
}

// ---------------------------------------------------------------- flash attention v3: 32x32 MFMA,
// swapped QK^T, in-register P (T12). Per wave: 32 q-rows (B-operand cols), KVBLK=64.
//   QK: sa[kb] = mfma(K_rows, Q_cols) -> lane holds P[q=lane&31][32 k-values] IN REGISTERS.
//   softmax: per-lane scalar exp/accumulate (no LDS round-trip, no shuffles until epilogue).
//   P->A-frag: v_cvt_pk_bf16_f32 pairs + permlane32_swap (verified pairing vs m74/m101 C/D map).
//   PV: o[db] = mfma(P_frag, Vt_rows).
// Staging schedule & swizzles identical to the verified R2 kernel:
//   QK(kt) -> BAR_A -> cp16 K/Im(kt+1) -> exp/pack -> PV(kt) -> BAR_B -> cp16 Vt(kt+1)
__global__ __launch_bounds__(256) void attn(const short* __restrict__ Qp,
                                            const short* __restrict__ Kp,
                                            const short* __restrict__ VtG,
                                            const short* __restrict__ Imb,
                                            short* __restrict__ attnA) {
  const int qb = blockIdx.y * 128;
  const int bh = blockIdx.x;
  const int b = bh >> 4, h = bh & 15;
  const int t = threadIdx.x, lane = t & 63, w = t >> 6;   // w: 0..3
  const int c31 = lane & 31;       // q-row (QK out col / PV A row) and d-row (PV out col)
  const int hi  = lane >> 5;       // half-wave: k-slice selector
  const int lrow8 = lane >> 3, lchunk = lane & 7;
  const int gch = lchunk ^ lrow8;  // staging swizzle: LDS[row][ch] = G[row][ch ^ (row&7)]

  __shared__ __align__(16) short tiles[3 * 64 * 64];   // K | Im | Vt  (24576 B)

  // Q/Im B-fragments in regs: lane holds row (qb + w*32 + c31), k = ks*16 + hi*8 .. +8
  const int qrow = qb + w * 32 + c31;
  const size_t qbase = ((size_t)(b * SEQ + qrow)) * EMB + h * HDIM + hi * 8;
  short8 bq_[4], bim[4];
  #pragma unroll
  for (int ks = 0; ks < 4; ++ks) {
    bq_[ks] = *(const short8*)&Qp [qbase + ks * 16];
    bim[ks] = *(const short8*)&Imb[qbase + ks * 16];
  }

  float lrA = 0.f, lrB = 0.f;      // per-lane softmax denominator (q = qrow), split chains
  f32x16 o0 = {}, o1 = {};         // PV accum, d-blocks 0/1

  const float SC = 0.03125f * 1.44269504089f;   // /sqrt(1024) * log2(e)
  const size_t kimBase = ((size_t)b * SEQ) * EMB + h * HDIM + gch * 8;
  const size_t vtBase  = ((size_t)bh * HDIM) * SEQ + gch * 8;

  // prologue: stage all of tile 0 (6 cp16 per wave = 24 total = 3 x 8 KB)
  #pragma unroll
  for (int s = 0; s < 6; ++s) {
    const int I = w * 6 + s;
    const int tz = I >> 3;
    const int row = ((I & 7) * 8) + lrow8;
    const short* g;
    if (tz == 0)      g = Kp  + kimBase + (size_t)row * EMB;
    else if (tz == 1) g = Imb + kimBase + (size_t)row * EMB;
    else              g = VtG + vtBase + (size_t)row * SEQ;
    cp16(g, &tiles[I * 512]);
  }
  __syncthreads();

  const int swz = c31 & 7;         // row-XOR (same for rows c31 and 32+c31)

  for (int kt = 0; kt < 16; ++kt) {
    const int kBaseN = (kt + 1) * 64;   // next tile base (unused when kt==15)

    // ---- QK phase (swapped): out row = k, col = q. A = K/Im rows from LDS, B = Q/Im regs.
    f32x16 s0 = {}, s1 = {};
    #pragma unroll
    for (int ks = 0; ks < 4; ++ks) {
      const int ch = ((ks * 2 + hi) ^ swz) * 8;
      const int r0off = c31 * 64 + ch, r1off = (32 + c31) * 64 + ch;
      short8 k0 = *(const short8*)&tiles[r0off];
      short8 k1 = *(const short8*)&tiles[r1off];
      short8 i0 = *(const short8*)&tiles[4096 + r0off];
      short8 i1 = *(const short8*)&tiles[4096 + r1off];
      s0 = __builtin_amdgcn_mfma_f32_32x32x16_bf16(k0, bq_[ks], s0, 0, 0, 0);
      s1 = __builtin_amdgcn_mfma_f32_32x32x16_bf16(k1, bq_[ks], s1, 0, 0, 0);
      s0 = __builtin_amdgcn_mfma_f32_32x32x16_bf16(i0, bim[ks], s0, 0, 0, 0);
      s1 = __builtin_amdgcn_mfma_f32_32x32x16_bf16(i1, bim[ks], s1, 0, 0, 0);
    }

    __syncthreads();   // BAR_A: all waves done reading K/Im(kt); Vt(kt) committed

    // ---- stage K/Im for kt+1 (4 cp16 per wave = 16 KB); commits at BAR_B
    if (kt != 15) {
      #pragma unroll
      for (int s = 0; s < 4; ++s) {
        const int I = w * 4 + s;            // 0..15
        const int row = ((I & 7) * 8) + lrow8;
        const short* g = ((I >> 3) ? Imb : Kp) + kimBase + (size_t)(kBaseN + row) * EMB;
        cp16(g, &tiles[I * 512]);
      }
    }

    // ---- exp, fully in-register. Lane L holds P[q=c31][k = (reg&3)+8*(reg>>2)+4*hi (+32 for s1)]
    float p0[16], p1[16];
    #pragma unroll
    for (int r = 0; r < 16; ++r) {
      p0[r] = __builtin_amdgcn_exp2f(s0[r] * SC);
      p1[r] = __builtin_amdgcn_exp2f(s1[r] * SC);
      lrA += p0[r];
      lrB += p1[r];
    }

    // ---- pack P -> PV A-frags via cvt_pk + permlane32_swap.
    // frag[ks] elems e: k = ks*16 + hi*8 + e. Pairs (p0,p1)&(p4,p5) -> words 0,2; (p2,p3)&(p6,p7) -> 1,3.
    short8 ap[4];
    #pragma unroll
    for (int half = 0; half < 2; ++half) {        // regs 0..7 / 8..15 -> ks = 2*kb + half
      {
        u32x2 sA = __builtin_amdgcn_permlane32_swap(
            cvt_pk_bf16(p0[half*8+0], p0[half*8+1]), cvt_pk_bf16(p0[half*8+4], p0[half*8+5]), false, false);
        u32x2 sB = __builtin_amdgcn_permlane32_swap(
            cvt_pk_bf16(p0[half*8+2], p0[half*8+3]), cvt_pk_bf16(p0[half*8+6], p0[half*8+7]), false, false);
        u32x4 wv = {sA[0], sB[0], sA[1], sB[1]};
        ap[half] = __builtin_bit_cast(short8, wv);
      }
      {
        u32x2 sA = __builtin_amdgcn_permlane32_swap(
            cvt_pk_bf16(p1[half*8+0], p1[half*8+1]), cvt_pk_bf16(p1[half*8+4], p1[half*8+5]), false, false);
        u32x2 sB = __builtin_amdgcn_permlane32_swap(
            cvt_pk_bf16(p1[half*8+2], p1[half*8+3]), cvt_pk_bf16(p1[half*8+6], p1[half*8+7]), false, false);
        u32x4 wv = {sA[0], sB[0], sA[1], sB[1]};
        ap[2 + half] = __builtin_bit_cast(short8, wv);
      }
    }

    // ---- PV phase: A = P frags, B = Vt rows (d = db*32 + c31) from LDS. out col = d, row = q.
    #pragma unroll
    for (int ks = 0; ks < 4; ++ks) {
      const int ch = ((ks * 2 + hi) ^ swz) * 8;
      short8 v0 = *(const short8*)&tiles[8192 + c31 * 64 + ch];
      short8 v1 = *(const short8*)&tiles[8192 + (32 + c31) * 64 + ch];
      o0 = __builtin_amdgcn_mfma_f32_32x32x16_bf16(ap[ks], v0, o0, 0, 0, 0);
      o1 = __builtin_amdgcn_mfma_f32_32x32x16_bf16(ap[ks], v1, o1, 0, 0, 0);
    }

    __syncthreads();   // BAR_B: all waves done reading Vt(kt); K/Im(kt+1) committed

    // ---- stage Vt for kt+1 (2 cp16 per wave = 8 KB); commits at next BAR_A
    if (kt != 15) {
      #pragma unroll
      for (int s = 0; s < 2; ++s) {
        const int I = 16 + w * 2 + s;       // 16..23
        const int row = ((I & 7) * 8) + lrow8;
        cp16(VtG + vtBase + (size_t)row * SEQ + kBaseN, &tiles[I * 512]);
      }
    }
  }

  // epilogue: lane pair (L, L+32) hold disjoint k-halves of q=c31's denominator
  float lr = lrA + lrB;
  lr += __shfl_xor(lr, 32);
  float inv = 1.f / lr;                  // valid for q-row (qb + w*32 + c31), all lanes

  // o[db][r] = O[q = qb+w*32+(r&3)+8*(r>>2)+4*hi][d = db*32 + c31]
  #pragma unroll
  for (int r = 0; r < 16; ++r) {
    const int qr = (r & 3) + 8 * (r >> 2) + 4 * hi;
    const float invr = __shfl(inv, qr);  // lane qr holds inv for q-row qb+w*32+qr
    const size_t base = ((size_t)(b * SEQ + qb + w * 32 + qr)) * EMB + h * HDIM + c31;
    attnA[base]      = (short)f2bf_fast(o0[r] * invr);
    attnA[base + 32] = (short)f2bf_fast(o1[r] * invr);
  }
}

// ---------------------------------------------------------------- launch
extern "C" void kernel_launch(void* const* d_in, const int* in_sizes, int n_in,
                              void* d_out, int out_size, void* d_ws, size_t ws_size,
                              hipStream_t stream) {
  const float* Re  = (const float*)d_in[0];
  const float* Im  = (const float*)d_in[1];
  const float* pos = (const float*)d_in[2];
  const float* Wq  = (const float*)d_in[3];
  const float* bq  = (const float*)d_in[4];
  const float* Wk  = (const float*)d_in[5];
  const float* bk  = (const float*)d_in[6];
  const float* Wv  = (const float*)d_in[7];
  const float* bv  = (const float*)d_in[8];
  const float* Wo  = (const float*)d_in[9];
  const float* bo  = (const float*)d_in[10];

  short* ws    = (short*)d_ws;
  short* Rebf  = ws;                         // 4M shorts
  short* Imbf  = ws + (size_t)MELEM;         // 4M
  short* Wt    = ws + (size_t)2 * MELEM;     // 4 x 1M (q,k,v,o)
  short* Qp    = ws + (size_t)3 * MELEM;     // Q,K projections + Vt: 3 x 4M
  short* Kp    = Qp + (size_t)MELEM;
  short* VtG   = Qp + (size_t)2 * MELEM;     // V transposed [b,h,d,s]
  short* attnA = ws + (size_t)6 * MELEM;     // 4M

  cvt_bf16<<<dim3(MELEM / 1024, 2), 256, 0, stream>>>(Re, Im, Rebf, Imbf);

  wtrans<<<dim3(32, 32, 4), dim3(32, 8), 0, stream>>>(Wq, Wk, Wv, Wo, Wt);

  // fused Q/K/V projection (+bias +P), bf16 out; V written transposed. N fused to 3072.
  gemm_qkv<<<dim3(3 * EMB / 64, MTOT / 128), 256, 0, stream>>>(
      Rebf, Wt, bq, bk, bv, pos, Qp, VtG);

  // flash attention (x = bh for XCD-local L2 reuse of K/Im/Vt), 128-row q-tiles
  attn<<<dim3(BATCH * NHEAD, SEQ / 128), 256, 0, stream>>>(
      Qp, Kp, VtG, Imbf, attnA);

  // output projection, f32 out, 64x64 tiles for 4 blocks/CU
  gemm_wo<<<dim3(EMB / 64, MTOT / 64), 256, 0, stream>>>(
      attnA, Wt + 3 * EMB * EMB, bo, (float*)d_out);
}

// Round 4
// 191.629 us; speedup vs baseline: 1.1022x; 1.0110x over previous
//
#include <hip/hip_runtime.h>
#include <hip/hip_bf16.h>
#include <stdint.h>

// Problem constants
#define BATCH 4
#define SEQ   1024
#define EMB   1024
#define NHEAD 16
#define HDIM  64
#define MTOT  (BATCH*SEQ)          // 4096 rows
#define MELEM (MTOT*EMB)           // 4,194,304 elements per [B,S,E] tensor

typedef __attribute__((ext_vector_type(8))) short short8;
typedef __attribute__((ext_vector_type(4))) float f32x4;
typedef __attribute__((ext_vector_type(16))) float f32x16;
typedef __attribute__((ext_vector_type(4))) unsigned short us4;
typedef __attribute__((ext_vector_type(2))) unsigned int u32x2;
typedef __attribute__((ext_vector_type(4))) unsigned int u32x4;

// fast f32->bf16: round-half-up via integer add (inputs finite, no NaN).
static __device__ __forceinline__ unsigned short f2bf_fast(float f) {
  unsigned u = __builtin_bit_cast(unsigned, f);
  return (unsigned short)((u + 0x8000u) >> 16);
}

// packed f32x2 -> bf16x2 (RNE), no builtin on gfx950 (T12/m240) -> inline asm
static __device__ __forceinline__ unsigned cvt_pk_bf16(float lo, float hi) {
  unsigned r;
  asm("v_cvt_pk_bf16_f32 %0, %1, %2" : "=v"(r) : "v"(lo), "v"(hi));
  return r;
}

// async global->LDS, 16B per lane. lds ptr must be WAVE-UNIFORM base;
// HW scatters lane i to base + i*16. (m97 recipe)
static __device__ __forceinline__ void cp16(const void* g, const void* lds_uniform) {
  __builtin_amdgcn_global_load_lds(
      (const __attribute__((address_space(1))) unsigned int*)(uintptr_t)g,
      (__attribute__((address_space(3))) unsigned int*)(unsigned int)(uintptr_t)lds_uniform,
      16, 0, 0);
}

// ---------------------------------------------------------------- prep: cvt f32->bf16 (Re,Im) + W transpose x4
// Fused into one launch (both memory-bound, independent) to drop one launch gap.
// bid 0..4095: Re cvt | 4096..8191: Im cvt | 8192..12287: wtrans (z = (bid-8192)>>10)
__global__ __launch_bounds__(256) void prep(const float* __restrict__ Re,
                                            const float* __restrict__ Im,
                                            short* __restrict__ Rebf,
                                            short* __restrict__ Imbf,
                                            const float* __restrict__ W0,
                                            const float* __restrict__ W1,
                                            const float* __restrict__ W2,
                                            const float* __restrict__ W3,
                                            short* __restrict__ WtBase) {
  __shared__ short tile[32][33];
  const int bid = blockIdx.x;
  if (bid < 8192) {
    const float* in  = (bid >= 4096) ? Im   : Re;
    short*       out = (bid >= 4096) ? Imbf : Rebf;
    int i = (bid & 4095) * 256 + threadIdx.x;   // each thread: 4 elements
    float4 f = ((const float4*)in)[i];
    unsigned r0 = ((unsigned)f2bf_fast(f.y) << 16) | f2bf_fast(f.x);
    unsigned r1 = ((unsigned)f2bf_fast(f.w) << 16) | f2bf_fast(f.z);
    ((uint2*)out)[i] = make_uint2(r0, r1);
  } else {
    const int wb = bid - 8192;
    const int z = wb >> 10;
    const float* W = (z == 0) ? W0 : (z == 1) ? W1 : (z == 2) ? W2 : W3;
    short* Wt = WtBase + (size_t)z * EMB * EMB;
    const int rem = wb & 1023;
    const int nT = (rem & 31) * 32, kT = (rem >> 5) * 32;
    const int tx = threadIdx.x & 31, ty = threadIdx.x >> 5;   // 32 x 8
    #pragma unroll
    for (int i = 0; i < 4; ++i)
      tile[ty + 8*i][tx] = (short)f2bf_fast(W[(size_t)(kT + ty + 8*i) * EMB + nT + tx]);
    __syncthreads();
    #pragma unroll
    for (int i = 0; i < 4; ++i)
      Wt[(size_t)(nT + ty + 8*i) * EMB + kT + tx] = tile[tx][ty + 8*i];
  }
}

// ---------------------------------------------------------------- fused QKV GEMM, 128x64 tiles
// N fused to 3072 (Wt holds Wq^T|Wk^T|Wv^T contiguous). grid (48,32) = 1536 blocks.
// R4: double-buffered LDS (48 KB, 3 blocks/CU), ONE barrier per K-step (T3 min-2-phase):
//   stage(next, buf^1) issued BEFORE compute(cur) -> HBM latency hides under 16 MFMAs;
//   single __syncthreads (compiler emits vmcnt(0)+lgkmcnt(0) drain) per step. 17 barriers vs 32.
__global__ __launch_bounds__(256) void gemm_qkv(const short* __restrict__ A,
                                                const short* __restrict__ Wt,
                                                const float* __restrict__ bq,
                                                const float* __restrict__ bk,
                                                const float* __restrict__ bv,
                                                const float* __restrict__ pos,
                                                short* __restrict__ QKbase,
                                                short* __restrict__ vtOut) {
  const int m0 = blockIdx.y * 128, n0 = blockIdx.x * 64;
  const int z = n0 >> 10;                       // 0=Q 1=K 2=V (64-tile never crosses)
  const float* bias = (z == 0) ? bq : (z == 1 ? bk : bv);

  __shared__ __align__(16) short As[2][128 * 64];  // 2 x 16 KB
  __shared__ __align__(16) short Bs[2][64 * 64];   // 2 x 8 KB

  const int t = threadIdx.x;
  const int lane = t & 63, w = t >> 6;
  const int wm = w >> 1, wn = w & 1;            // wave tile 64m x 32n
  const int quad = lane >> 4, l16 = lane & 15;
  const int lrow8 = lane >> 3, lchunk = lane & 7;
  const int gch = lchunk ^ lrow8;               // swizzled source chunk
  const int sw7 = l16 & 7;

  const short* Arow = A  + (size_t)(m0 + w * 32 + lrow8) * EMB + gch * 8;
  const short* Brow = Wt + (size_t)(n0 + w * 16 + lrow8) * EMB + gch * 8;

  f32x4 acc[4][2] = {};

  auto STAGE = [&](short* as, short* bs, int k0) {
    #pragma unroll
    for (int s = 0; s < 4; ++s)
      cp16(Arow + (size_t)(s * 8) * EMB + k0, &as[(w * 32 + s * 8) * 64]);
    #pragma unroll
    for (int s = 0; s < 2; ++s)
      cp16(Brow + (size_t)(s * 8) * EMB + k0, &bs[(w * 16 + s * 8) * 64]);
  };
  auto COMPUTE = [&](const short* as, const short* bs) {
    #pragma unroll
    for (int ks = 0; ks < 2; ++ks) {
      const int chv = ((ks << 2) + quad) ^ sw7;
      short8 af[4], bfr[2];
      #pragma unroll
      for (int i = 0; i < 4; ++i)
        af[i] = *(const short8*)&as[(wm * 64 + i * 16 + l16) * 64 + chv * 8];
      #pragma unroll
      for (int j = 0; j < 2; ++j)
        bfr[j] = *(const short8*)&bs[(wn * 32 + j * 16 + l16) * 64 + chv * 8];
      #pragma unroll
      for (int i = 0; i < 4; ++i)
        #pragma unroll
        for (int j = 0; j < 2; ++j)
          acc[i][j] = __builtin_amdgcn_mfma_f32_16x16x32_bf16(af[i], bfr[j], acc[i][j], 0, 0, 0);
    }
  };

  STAGE(As[0], Bs[0], 0);
  __syncthreads();                       // buf0 (k=0) ready

  for (int p = 0; p < 8; ++p) {          // 16 K-steps, pairs (2p, 2p+1)
    STAGE(As[1], Bs[1], p * 128 + 64);   // issue next (always exists: max 960)
    COMPUTE(As[0], Bs[0]);               // k = p*128
    __syncthreads();                     // drains own cp16s; buf1 ready, buf0 free
    if (p != 7)
      STAGE(As[0], Bs[0], p * 128 + 128);
    COMPUTE(As[1], Bs[1]);               // k = p*128 + 64
    __syncthreads();
  }

  // epilogue: C row = quad*4+r, col = l16
  #pragma unroll
  for (int i = 0; i < 4; ++i) {
    int mbase = m0 + wm * 64 + i * 16 + quad * 4;
    #pragma unroll
    for (int j = 0; j < 2; ++j) {
      int n = n0 + wn * 32 + j * 16 + l16;
      int nl = n & 1023;
      float bn = bias[nl];
      int d = nl & (HDIM - 1);
      if (z == 2) {
        // write V transposed: [b,h,d,s] so attn stages Vt rows contiguously
        int bh = (mbase >> 10) * NHEAD + (nl >> 6);
        int s = mbase & (SEQ - 1);
        us4 pk;
        #pragma unroll
        for (int r = 0; r < 4; ++r) {
          float v = acc[i][j][r] + bn + pos[(size_t)(mbase + r) * HDIM + d];
          pk[r] = f2bf_fast(v);
        }
        *(us4*)&vtOut[((size_t)bh * HDIM + d) * SEQ + s] = pk;
      } else {
        #pragma unroll
        for (int r = 0; r < 4; ++r) {
          int mm = mbase + r;
          float v = acc[i][j][r] + bn + pos[(size_t)mm * HDIM + d];
          QKbase[(size_t)z * MELEM + (size_t)mm * EMB + nl] = (short)f2bf_fast(v);
        }
      }
    }
  }
}

// ---------------------------------------------------------------- Wo GEMM: 64x64 tiles, double-buffered
// Same 1-barrier-per-K-step transform (LDS 32 KB -> 5 blocks/CU).
__global__ __launch_bounds__(256) void gemm_wo(const short* __restrict__ A,
                                               const short* __restrict__ Bt,
                                               const float* __restrict__ bias,
                                               float* __restrict__ out) {
  const int m0 = blockIdx.y * 64, n0 = blockIdx.x * 64;

  __shared__ __align__(16) short As[2][64 * 64];
  __shared__ __align__(16) short Bs[2][64 * 64];

  const int t = threadIdx.x;
  const int lane = t & 63, w = t >> 6;
  const int wm = w >> 1, wn = w & 1;          // wave tile: 32m x 32n
  const int quad = lane >> 4, l16 = lane & 15;
  const int lrow8 = lane >> 3, lchunk = lane & 7;
  const int gch = lchunk ^ lrow8;
  const int sw7 = l16 & 7;

  const short* Arow = A  + (size_t)(m0 + w * 16 + lrow8) * EMB + gch * 8;
  const short* Brow = Bt + (size_t)(n0 + w * 16 + lrow8) * EMB + gch * 8;

  f32x4 acc[2][2] = {};

  auto STAGE = [&](short* as, short* bs, int k0) {
    #pragma unroll
    for (int s = 0; s < 2; ++s) {
      cp16(Arow + (size_t)(s * 8) * EMB + k0, &as[(w * 16 + s * 8) * 64]);
      cp16(Brow + (size_t)(s * 8) * EMB + k0, &bs[(w * 16 + s * 8) * 64]);
    }
  };
  auto COMPUTE = [&](const short* as, const short* bs) {
    #pragma unroll
    for (int ks = 0; ks < 2; ++ks) {
      const int chv = ((ks << 2) + quad) ^ sw7;
      short8 af[2], bfr[2];
      #pragma unroll
      for (int i = 0; i < 2; ++i)
        af[i] = *(const short8*)&as[(wm * 32 + i * 16 + l16) * 64 + chv * 8];
      #pragma unroll
      for (int j = 0; j < 2; ++j)
        bfr[j] = *(const short8*)&bs[(wn * 32 + j * 16 + l16) * 64 + chv * 8];
      #pragma unroll
      for (int i = 0; i < 2; ++i)
        #pragma unroll
        for (int j = 0; j < 2; ++j)
          acc[i][j] = __builtin_amdgcn_mfma_f32_16x16x32_bf16(af[i], bfr[j], acc[i][j], 0, 0, 0);
    }
  };

  STAGE(As[0], Bs[0], 0);
  __syncthreads();

  for (int p = 0; p < 8; ++p) {
    STAGE(As[1], Bs[1], p * 128 + 64);
    COMPUTE(As[0], Bs[0]);
    __syncthreads();
    if (p != 7)
      STAGE(As[0], Bs[0], p * 128 + 128);
    COMPUTE(As[1], Bs[1]);
    __syncthreads();
  }

  #pragma unroll
  for (int i = 0; i < 2; ++i) {
    int mbase = m0 + wm * 32 + i * 16 + quad * 4;
    #pragma unroll
    for (int j = 0; j < 2; ++j) {
      int n = n0 + wn * 32 + j * 16 + l16;
      float bn = bias[n];
      #pragma unroll
      for (int r = 0; r < 4; ++r)
        out[(size_t)(mbase + r) * EMB + n] = acc[i][j][r] + bn;
    }
  }
}

// ---------------------------------------------------------------- flash attention v3: 32x32 MFMA,
// swapped QK^T, in-register P (T12). Per wave: 32 q-rows (B-operand cols), KVBLK=64.
//   QK: sa[kb] = mfma(K_rows, Q_cols) -> lane holds P[q=lane&31][32 k-values] IN REGISTERS.
//   softmax: per-lane scalar exp/accumulate (no LDS round-trip, no shuffles until epilogue).
//   P->A-frag: v_cvt_pk_bf16_f32 pairs + permlane32_swap (verified pairing vs m74/m101 C/D map).
//   PV: o[db] = mfma(P_frag, Vt_rows).
// Staging schedule & swizzles identical to the verified R2 kernel:
//   QK(kt) -> BAR_A -> cp16 K/Im(kt+1) -> exp/pack -> PV(kt) -> BAR_B -> cp16 Vt(kt+1)
__global__ __launch_bounds__(256) void attn(const short* __restrict__ Qp,
                                            const short* __restrict__ Kp,
                                            const short* __restrict__ VtG,
                                            const short* __restrict__ Imb,
                                            short* __restrict__ attnA) {
  const int qb = blockIdx.y * 128;
  const int bh = blockIdx.x;
  const int b = bh >> 4, h = bh & 15;
  const int t = threadIdx.x, lane = t & 63, w = t >> 6;   // w: 0..3
  const int c31 = lane & 31;       // q-row (QK out col / PV A row) and d-row (PV out col)
  const int hi  = lane >> 5;       // half-wave: k-slice selector
  const int lrow8 = lane >> 3, lchunk = lane & 7;
  const int gch = lchunk ^ lrow8;  // staging swizzle: LDS[row][ch] = G[row][ch ^ (row&7)]

  __shared__ __align__(16) short tiles[3 * 64 * 64];   // K | Im | Vt  (24576 B)

  // Q/Im B-fragments in regs: lane holds row (qb + w*32 + c31), k = ks*16 + hi*8 .. +8
  const int qrow = qb + w * 32 + c31;
  const size_t qbase = ((size_t)(b * SEQ + qrow)) * EMB + h * HDIM + hi * 8;
  short8 bq_[4], bim[4];
  #pragma unroll
  for (int ks = 0; ks < 4; ++ks) {
    bq_[ks] = *(const short8*)&Qp [qbase + ks * 16];
    bim[ks] = *(const short8*)&Imb[qbase + ks * 16];
  }

  float lrA = 0.f, lrB = 0.f;      // per-lane softmax denominator (q = qrow), split chains
  f32x16 o0 = {}, o1 = {};         // PV accum, d-blocks 0/1

  const float SC = 0.03125f * 1.44269504089f;   // /sqrt(1024) * log2(e)
  const size_t kimBase = ((size_t)b * SEQ) * EMB + h * HDIM + gch * 8;
  const size_t vtBase  = ((size_t)bh * HDIM) * SEQ + gch * 8;

  // prologue: stage all of tile 0 (6 cp16 per wave = 24 total = 3 x 8 KB)
  #pragma unroll
  for (int s = 0; s < 6; ++s) {
    const int I = w * 6 + s;
    const int tz = I >> 3;
    const int row = ((I & 7) * 8) + lrow8;
    const short* g;
    if (tz == 0)      g = Kp  + kimBase + (size_t)row * EMB;
    else if (tz == 1) g = Imb + kimBase + (size_t)row * EMB;
    else              g = VtG + vtBase + (size_t)row * SEQ;
    cp16(g, &tiles[I * 512]);
  }
  __syncthreads();

  const int swz = c31 & 7;         // row-XOR (same for rows c31 and 32+c31)

  for (int kt = 0; kt < 16; ++kt) {
    const int kBaseN = (kt + 1) * 64;   // next tile base (unused when kt==15)

    // ---- QK phase (swapped): out row = k, col = q. A = K/Im rows from LDS, B = Q/Im regs.
    f32x16 s0 = {}, s1 = {};
    #pragma unroll
    for (int ks = 0; ks < 4; ++ks) {
      const int ch = ((ks * 2 + hi) ^ swz) * 8;
      const int r0off = c31 * 64 + ch, r1off = (32 + c31) * 64 + ch;
      short8 k0 = *(const short8*)&tiles[r0off];
      short8 k1 = *(const short8*)&tiles[r1off];
      short8 i0 = *(const short8*)&tiles[4096 + r0off];
      short8 i1 = *(const short8*)&tiles[4096 + r1off];
      s0 = __builtin_amdgcn_mfma_f32_32x32x16_bf16(k0, bq_[ks], s0, 0, 0, 0);
      s1 = __builtin_amdgcn_mfma_f32_32x32x16_bf16(k1, bq_[ks], s1, 0, 0, 0);
      s0 = __builtin_amdgcn_mfma_f32_32x32x16_bf16(i0, bim[ks], s0, 0, 0, 0);
      s1 = __builtin_amdgcn_mfma_f32_32x32x16_bf16(i1, bim[ks], s1, 0, 0, 0);
    }

    __syncthreads();   // BAR_A: all waves done reading K/Im(kt); Vt(kt) committed

    // ---- stage K/Im for kt+1 (4 cp16 per wave = 16 KB); commits at BAR_B
    if (kt != 15) {
      #pragma unroll
      for (int s = 0; s < 4; ++s) {
        const int I = w * 4 + s;            // 0..15
        const int row = ((I & 7) * 8) + lrow8;
        const short* g = ((I >> 3) ? Imb : Kp) + kimBase + (size_t)(kBaseN + row) * EMB;
        cp16(g, &tiles[I * 512]);
      }
    }

    // ---- exp, fully in-register. Lane L holds P[q=c31][k = (reg&3)+8*(reg>>2)+4*hi (+32 for s1)]
    float p0[16], p1[16];
    #pragma unroll
    for (int r = 0; r < 16; ++r) {
      p0[r] = __builtin_amdgcn_exp2f(s0[r] * SC);
      p1[r] = __builtin_amdgcn_exp2f(s1[r] * SC);
      lrA += p0[r];
      lrB += p1[r];
    }

    // ---- pack P -> PV A-frags via cvt_pk + permlane32_swap.
    // frag[ks] elems e: k = ks*16 + hi*8 + e. Pairs (p0,p1)&(p4,p5) -> words 0,2; (p2,p3)&(p6,p7) -> 1,3.
    short8 ap[4];
    #pragma unroll
    for (int half = 0; half < 2; ++half) {        // regs 0..7 / 8..15 -> ks = 2*kb + half
      {
        u32x2 sA = __builtin_amdgcn_permlane32_swap(
            cvt_pk_bf16(p0[half*8+0], p0[half*8+1]), cvt_pk_bf16(p0[half*8+4], p0[half*8+5]), false, false);
        u32x2 sB = __builtin_amdgcn_permlane32_swap(
            cvt_pk_bf16(p0[half*8+2], p0[half*8+3]), cvt_pk_bf16(p0[half*8+6], p0[half*8+7]), false, false);
        u32x4 wv = {sA[0], sB[0], sA[1], sB[1]};
        ap[half] = __builtin_bit_cast(short8, wv);
      }
      {
        u32x2 sA = __builtin_amdgcn_permlane32_swap(
            cvt_pk_bf16(p1[half*8+0], p1[half*8+1]), cvt_pk_bf16(p1[half*8+4], p1[half*8+5]), false, false);
        u32x2 sB = __builtin_amdgcn_permlane32_swap(
            cvt_pk_bf16(p1[half*8+2], p1[half*8+3]), cvt_pk_bf16(p1[half*8+6], p1[half*8+7]), false, false);
        u32x4 wv = {sA[0], sB[0], sA[1], sB[1]};
        ap[2 + half] = __builtin_bit_cast(short8, wv);
      }
    }

    // ---- PV phase: A = P frags, B = Vt rows (d = db*32 + c31) from LDS. out col = d, row = q.
    #pragma unroll
    for (int ks = 0; ks < 4; ++ks) {
      const int ch = ((ks * 2 + hi) ^ swz) * 8;
      short8 v0 = *(const short8*)&tiles[8192 + c31 * 64 + ch];
      short8 v1 = *(const short8*)&tiles[8192 + (32 + c31) * 64 + ch];
      o0 = __builtin_amdgcn_mfma_f32_32x32x16_bf16(ap[ks], v0, o0, 0, 0, 0);
      o1 = __builtin_amdgcn_mfma_f32_32x32x16_bf16(ap[ks], v1, o1, 0, 0, 0);
    }

    __syncthreads();   // BAR_B: all waves done reading Vt(kt); K/Im(kt+1) committed

    // ---- stage Vt for kt+1 (2 cp16 per wave = 8 KB); commits at next BAR_A
    if (kt != 15) {
      #pragma unroll
      for (int s = 0; s < 2; ++s) {
        const int I = 16 + w * 2 + s;       // 16..23
        const int row = ((I & 7) * 8) + lrow8;
        cp16(VtG + vtBase + (size_t)row * SEQ + kBaseN, &tiles[I * 512]);
      }
    }
  }

  // epilogue: lane pair (L, L+32) hold disjoint k-halves of q=c31's denominator
  float lr = lrA + lrB;
  lr += __shfl_xor(lr, 32);
  float inv = 1.f / lr;                  // valid for q-row (qb + w*32 + c31), all lanes

  // o[db][r] = O[q = qb+w*32+(r&3)+8*(r>>2)+4*hi][d = db*32 + c31]
  #pragma unroll
  for (int r = 0; r < 16; ++r) {
    const int qr = (r & 3) + 8 * (r >> 2) + 4 * hi;
    const float invr = __shfl(inv, qr);  // lane qr holds inv for q-row qb+w*32+qr
    const size_t base = ((size_t)(b * SEQ + qb + w * 32 + qr)) * EMB + h * HDIM + c31;
    attnA[base]      = (short)f2bf_fast(o0[r] * invr);
    attnA[base + 32] = (short)f2bf_fast(o1[r] * invr);
  }
}

// ---------------------------------------------------------------- launch
extern "C" void kernel_launch(void* const* d_in, const int* in_sizes, int n_in,
                              void* d_out, int out_size, void* d_ws, size_t ws_size,
                              hipStream_t stream) {
  const float* Re  = (const float*)d_in[0];
  const float* Im  = (const float*)d_in[1];
  const float* pos = (const float*)d_in[2];
  const float* Wq  = (const float*)d_in[3];
  const float* bq  = (const float*)d_in[4];
  const float* Wk  = (const float*)d_in[5];
  const float* bk  = (const float*)d_in[6];
  const float* Wv  = (const float*)d_in[7];
  const float* bv  = (const float*)d_in[8];
  const float* Wo  = (const float*)d_in[9];
  const float* bo  = (const float*)d_in[10];

  short* ws    = (short*)d_ws;
  short* Rebf  = ws;                         // 4M shorts
  short* Imbf  = ws + (size_t)MELEM;         // 4M
  short* Wt    = ws + (size_t)2 * MELEM;     // 4 x 1M (q,k,v,o)
  short* Qp    = ws + (size_t)3 * MELEM;     // Q,K projections + Vt: 3 x 4M
  short* Kp    = Qp + (size_t)MELEM;
  short* VtG   = Qp + (size_t)2 * MELEM;     // V transposed [b,h,d,s]
  short* attnA = ws + (size_t)6 * MELEM;     // 4M

  // fused convert + weight transpose (one launch)
  prep<<<dim3(12288), 256, 0, stream>>>(Re, Im, Rebf, Imbf, Wq, Wk, Wv, Wo, Wt);

  // fused Q/K/V projection (+bias +P), bf16 out; V written transposed. N fused to 3072.
  gemm_qkv<<<dim3(3 * EMB / 64, MTOT / 128), 256, 0, stream>>>(
      Rebf, Wt, bq, bk, bv, pos, Qp, VtG);

  // flash attention (x = bh for XCD-local L2 reuse of K/Im/Vt), 128-row q-tiles
  attn<<<dim3(BATCH * NHEAD, SEQ / 128), 256, 0, stream>>>(
      Qp, Kp, VtG, Imbf, attnA);

  // output projection, f32 out, 64x64 tiles, double-buffered
  gemm_wo<<<dim3(EMB / 64, MTOT / 64), 256, 0, stream>>>(
      attnA, Wt + 3 * EMB * EMB, bo, (float*)d_out);
}

// Round 5
// 190.618 us; speedup vs baseline: 1.1081x; 1.0053x over previous
//
#include <hip/hip_runtime.h>
#include <hip/hip_bf16.h>
#include <stdint.h>

// Problem constants
#define BATCH 4
#define SEQ   1024
#define EMB   1024
#define NHEAD 16
#define HDIM  64
#define MTOT  (BATCH*SEQ)          // 4096 rows
#define MELEM (MTOT*EMB)           // 4,194,304 elements per [B,S,E] tensor

typedef __attribute__((ext_vector_type(8))) short short8;
typedef __attribute__((ext_vector_type(4))) float f32x4;
typedef __attribute__((ext_vector_type(16))) float f32x16;
typedef __attribute__((ext_vector_type(4))) unsigned short us4;
typedef __attribute__((ext_vector_type(2))) unsigned int u32x2;
typedef __attribute__((ext_vector_type(4))) unsigned int u32x4;

// counted vmem wait (T4): NEVER drain to 0 inside a pipelined loop.
#define WAITV(N) asm volatile("s_waitcnt vmcnt(" #N ")" ::: "memory")
#define BARRIER() __builtin_amdgcn_s_barrier()

// fast f32->bf16: round-half-up via integer add (inputs finite, no NaN).
static __device__ __forceinline__ unsigned short f2bf_fast(float f) {
  unsigned u = __builtin_bit_cast(unsigned, f);
  return (unsigned short)((u + 0x8000u) >> 16);
}

// packed f32x2 -> bf16x2 (RNE), no builtin on gfx950 (T12/m240) -> inline asm
static __device__ __forceinline__ unsigned cvt_pk_bf16(float lo, float hi) {
  unsigned r;
  asm("v_cvt_pk_bf16_f32 %0, %1, %2" : "=v"(r) : "v"(lo), "v"(hi));
  return r;
}

// async global->LDS, 16B per lane. lds ptr must be WAVE-UNIFORM base;
// HW scatters lane i to base + i*16. (m97 recipe)
static __device__ __forceinline__ void cp16(const void* g, const void* lds_uniform) {
  __builtin_amdgcn_global_load_lds(
      (const __attribute__((address_space(1))) unsigned int*)(uintptr_t)g,
      (__attribute__((address_space(3))) unsigned int*)(unsigned int)(uintptr_t)lds_uniform,
      16, 0, 0);
}

// ---------------------------------------------------------------- prep: cvt f32->bf16 (Re,Im) + W transpose x4
// bid 0..4095: Re cvt | 4096..8191: Im cvt | 8192..12287: wtrans (z = (bid-8192)>>10)
__global__ __launch_bounds__(256) void prep(const float* __restrict__ Re,
                                            const float* __restrict__ Im,
                                            short* __restrict__ Rebf,
                                            short* __restrict__ Imbf,
                                            const float* __restrict__ W0,
                                            const float* __restrict__ W1,
                                            const float* __restrict__ W2,
                                            const float* __restrict__ W3,
                                            short* __restrict__ WtBase) {
  __shared__ short tile[32][33];
  const int bid = blockIdx.x;
  if (bid < 8192) {
    const float* in  = (bid >= 4096) ? Im   : Re;
    short*       out = (bid >= 4096) ? Imbf : Rebf;
    int i = (bid & 4095) * 256 + threadIdx.x;   // each thread: 4 elements
    float4 f = ((const float4*)in)[i];
    unsigned r0 = ((unsigned)f2bf_fast(f.y) << 16) | f2bf_fast(f.x);
    unsigned r1 = ((unsigned)f2bf_fast(f.w) << 16) | f2bf_fast(f.z);
    ((uint2*)out)[i] = make_uint2(r0, r1);
  } else {
    const int wb = bid - 8192;
    const int z = wb >> 10;
    const float* W = (z == 0) ? W0 : (z == 1) ? W1 : (z == 2) ? W2 : W3;
    short* Wt = WtBase + (size_t)z * EMB * EMB;
    const int rem = wb & 1023;
    const int nT = (rem & 31) * 32, kT = (rem >> 5) * 32;
    const int tx = threadIdx.x & 31, ty = threadIdx.x >> 5;   // 32 x 8
    #pragma unroll
    for (int i = 0; i < 4; ++i)
      tile[ty + 8*i][tx] = (short)f2bf_fast(W[(size_t)(kT + ty + 8*i) * EMB + nT + tx]);
    __syncthreads();
    #pragma unroll
    for (int i = 0; i < 4; ++i)
      Wt[(size_t)(nT + ty + 8*i) * EMB + kT + tx] = tile[tx][ty + 8*i];
  }
}

// ---------------------------------------------------------------- fused QKV GEMM, 128x64 tiles
// N fused to 3072. grid (48,32) = 1536 blocks, 48 KB LDS -> 3 blocks/CU.
// R5: TRUE double-buffer pipeline (T3+T4). R4's __syncthreads drained vmcnt(0) at every
// barrier, killing the pipeline (the m97 ceiling). Now: counted WAITV(6) + raw s_barrier;
// each tile's 6 cp16s are issued TWO compute phases before use, loads never drain to 0.
__global__ __launch_bounds__(256) void gemm_qkv(const short* __restrict__ A,
                                                const short* __restrict__ Wt,
                                                const float* __restrict__ bq,
                                                const float* __restrict__ bk,
                                                const float* __restrict__ bv,
                                                const float* __restrict__ pos,
                                                short* __restrict__ QKbase,
                                                short* __restrict__ vtOut) {
  const int m0 = blockIdx.y * 128, n0 = blockIdx.x * 64;
  const int z = n0 >> 10;                       // 0=Q 1=K 2=V (64-tile never crosses)
  const float* bias = (z == 0) ? bq : (z == 1 ? bk : bv);

  __shared__ __align__(16) short As[2][128 * 64];  // 2 x 16 KB
  __shared__ __align__(16) short Bs[2][64 * 64];   // 2 x 8 KB

  const int t = threadIdx.x;
  const int lane = t & 63, w = t >> 6;
  const int wm = w >> 1, wn = w & 1;            // wave tile 64m x 32n
  const int quad = lane >> 4, l16 = lane & 15;
  const int lrow8 = lane >> 3, lchunk = lane & 7;
  const int gch = lchunk ^ lrow8;               // swizzled source chunk
  const int sw7 = l16 & 7;

  const short* Arow = A  + (size_t)(m0 + w * 32 + lrow8) * EMB + gch * 8;
  const short* Brow = Wt + (size_t)(n0 + w * 16 + lrow8) * EMB + gch * 8;

  f32x4 acc[4][2] = {};

  auto STAGE = [&](short* as, short* bs, int k0) {   // 6 cp16 per thread
    #pragma unroll
    for (int s = 0; s < 4; ++s)
      cp16(Arow + (size_t)(s * 8) * EMB + k0, &as[(w * 32 + s * 8) * 64]);
    #pragma unroll
    for (int s = 0; s < 2; ++s)
      cp16(Brow + (size_t)(s * 8) * EMB + k0, &bs[(w * 16 + s * 8) * 64]);
  };
  auto COMPUTE = [&](const short* as, const short* bs) {
    #pragma unroll
    for (int ks = 0; ks < 2; ++ks) {
      const int chv = ((ks << 2) + quad) ^ sw7;
      short8 af[4], bfr[2];
      #pragma unroll
      for (int i = 0; i < 4; ++i)
        af[i] = *(const short8*)&as[(wm * 64 + i * 16 + l16) * 64 + chv * 8];
      #pragma unroll
      for (int j = 0; j < 2; ++j)
        bfr[j] = *(const short8*)&bs[(wn * 32 + j * 16 + l16) * 64 + chv * 8];
      #pragma unroll
      for (int i = 0; i < 4; ++i)
        #pragma unroll
        for (int j = 0; j < 2; ++j)
          acc[i][j] = __builtin_amdgcn_mfma_f32_16x16x32_bf16(af[i], bfr[j], acc[i][j], 0, 0, 0);
    }
  };

  STAGE(As[0], Bs[0], 0);      // tile 0 in flight
  STAGE(As[1], Bs[1], 64);     // tile 1 in flight (12 loads outstanding)

  #pragma unroll 1
  for (int p = 0; p < 7; ++p) {
    WAITV(6); BARRIER();                    // own tile-(2p) loads done; all waves synced
    COMPUTE(As[0], Bs[0]);                  // k = p*128
    BARRIER();                              // all waves done reading buf0
    STAGE(As[0], Bs[0], p * 128 + 128);     // tile 2p+2
    WAITV(6); BARRIER();
    COMPUTE(As[1], Bs[1]);                  // k = p*128 + 64
    BARRIER();
    STAGE(As[1], Bs[1], p * 128 + 192);     // tile 2p+3
  }
  WAITV(6); BARRIER();
  COMPUTE(As[0], Bs[0]);                    // k = 896
  BARRIER();
  WAITV(0); BARRIER();
  COMPUTE(As[1], Bs[1]);                    // k = 960

  // epilogue: C row = quad*4+r, col = l16
  #pragma unroll
  for (int i = 0; i < 4; ++i) {
    int mbase = m0 + wm * 64 + i * 16 + quad * 4;
    #pragma unroll
    for (int j = 0; j < 2; ++j) {
      int n = n0 + wn * 32 + j * 16 + l16;
      int nl = n & 1023;
      float bn = bias[nl];
      int d = nl & (HDIM - 1);
      if (z == 2) {
        // write V transposed: [b,h,d,s] so attn stages Vt rows contiguously
        int bh = (mbase >> 10) * NHEAD + (nl >> 6);
        int s = mbase & (SEQ - 1);
        us4 pk;
        #pragma unroll
        for (int r = 0; r < 4; ++r) {
          float v = acc[i][j][r] + bn + pos[(size_t)(mbase + r) * HDIM + d];
          pk[r] = f2bf_fast(v);
        }
        *(us4*)&vtOut[((size_t)bh * HDIM + d) * SEQ + s] = pk;
      } else {
        #pragma unroll
        for (int r = 0; r < 4; ++r) {
          int mm = mbase + r;
          float v = acc[i][j][r] + bn + pos[(size_t)mm * HDIM + d];
          QKbase[(size_t)z * MELEM + (size_t)mm * EMB + nl] = (short)f2bf_fast(v);
        }
      }
    }
  }
}

// ---------------------------------------------------------------- Wo GEMM: 64x64 tiles, true pipeline
// Same counted-vmcnt transform; STAGE = 4 cp16/thread -> WAITV(4). 32 KB LDS, 5 blocks/CU.
__global__ __launch_bounds__(256) void gemm_wo(const short* __restrict__ A,
                                               const short* __restrict__ Bt,
                                               const float* __restrict__ bias,
                                               float* __restrict__ out) {
  const int m0 = blockIdx.y * 64, n0 = blockIdx.x * 64;

  __shared__ __align__(16) short As[2][64 * 64];
  __shared__ __align__(16) short Bs[2][64 * 64];

  const int t = threadIdx.x;
  const int lane = t & 63, w = t >> 6;
  const int wm = w >> 1, wn = w & 1;          // wave tile: 32m x 32n
  const int quad = lane >> 4, l16 = lane & 15;
  const int lrow8 = lane >> 3, lchunk = lane & 7;
  const int gch = lchunk ^ lrow8;
  const int sw7 = l16 & 7;

  const short* Arow = A  + (size_t)(m0 + w * 16 + lrow8) * EMB + gch * 8;
  const short* Brow = Bt + (size_t)(n0 + w * 16 + lrow8) * EMB + gch * 8;

  f32x4 acc[2][2] = {};

  auto STAGE = [&](short* as, short* bs, int k0) {   // 4 cp16 per thread
    #pragma unroll
    for (int s = 0; s < 2; ++s) {
      cp16(Arow + (size_t)(s * 8) * EMB + k0, &as[(w * 16 + s * 8) * 64]);
      cp16(Brow + (size_t)(s * 8) * EMB + k0, &bs[(w * 16 + s * 8) * 64]);
    }
  };
  auto COMPUTE = [&](const short* as, const short* bs) {
    #pragma unroll
    for (int ks = 0; ks < 2; ++ks) {
      const int chv = ((ks << 2) + quad) ^ sw7;
      short8 af[2], bfr[2];
      #pragma unroll
      for (int i = 0; i < 2; ++i)
        af[i] = *(const short8*)&as[(wm * 32 + i * 16 + l16) * 64 + chv * 8];
      #pragma unroll
      for (int j = 0; j < 2; ++j)
        bfr[j] = *(const short8*)&bs[(wn * 32 + j * 16 + l16) * 64 + chv * 8];
      #pragma unroll
      for (int i = 0; i < 2; ++i)
        #pragma unroll
        for (int j = 0; j < 2; ++j)
          acc[i][j] = __builtin_amdgcn_mfma_f32_16x16x32_bf16(af[i], bfr[j], acc[i][j], 0, 0, 0);
    }
  };

  STAGE(As[0], Bs[0], 0);
  STAGE(As[1], Bs[1], 64);

  #pragma unroll 1
  for (int p = 0; p < 7; ++p) {
    WAITV(4); BARRIER();
    COMPUTE(As[0], Bs[0]);
    BARRIER();
    STAGE(As[0], Bs[0], p * 128 + 128);
    WAITV(4); BARRIER();
    COMPUTE(As[1], Bs[1]);
    BARRIER();
    STAGE(As[1], Bs[1], p * 128 + 192);
  }
  WAITV(4); BARRIER();
  COMPUTE(As[0], Bs[0]);
  BARRIER();
  WAITV(0); BARRIER();
  COMPUTE(As[1], Bs[1]);

  #pragma unroll
  for (int i = 0; i < 2; ++i) {
    int mbase = m0 + wm * 32 + i * 16 + quad * 4;
    #pragma unroll
    for (int j = 0; j < 2; ++j) {
      int n = n0 + wn * 32 + j * 16 + l16;
      float bn = bias[n];
      #pragma unroll
      for (int r = 0; r < 4; ++r)
        out[(size_t)(mbase + r) * EMB + n] = acc[i][j][r] + bn;
    }
  }
}

// ---------------------------------------------------------------- flash attention v3: 32x32 MFMA,
// swapped QK^T, in-register P (T12). Per wave: 32 q-rows (B-operand cols), KVBLK=64.
//   QK: sa[kb] = mfma(K_rows, Q_cols) -> lane holds P[q=lane&31][32 k-values] IN REGISTERS.
//   softmax: per-lane scalar exp/accumulate (no LDS round-trip, no shuffles until epilogue).
//   P->A-frag: v_cvt_pk_bf16_f32 pairs + permlane32_swap (verified pairing vs m74/m101 C/D map).
//   PV: o[db] = mfma(P_frag, Vt_rows).
// Staging schedule & swizzles identical to the verified R2/R3 kernel (control this round):
//   QK(kt) -> BAR_A -> cp16 K/Im(kt+1) -> exp/pack -> PV(kt) -> BAR_B -> cp16 Vt(kt+1)
__global__ __launch_bounds__(256) void attn(const short* __restrict__ Qp,
                                            const short* __restrict__ Kp,
                                            const short* __restrict__ VtG,
                                            const short* __restrict__ Imb,
                                            short* __restrict__ attnA) {
  const int qb = blockIdx.y * 128;
  const int bh = blockIdx.x;
  const int b = bh >> 4, h = bh & 15;
  const int t = threadIdx.x, lane = t & 63, w = t >> 6;   // w: 0..3
  const int c31 = lane & 31;       // q-row (QK out col / PV A row) and d-row (PV out col)
  const int hi  = lane >> 5;       // half-wave: k-slice selector
  const int lrow8 = lane >> 3, lchunk = lane & 7;
  const int gch = lchunk ^ lrow8;  // staging swizzle: LDS[row][ch] = G[row][ch ^ (row&7)]

  __shared__ __align__(16) short tiles[3 * 64 * 64];   // K | Im | Vt  (24576 B)

  // Q/Im B-fragments in regs: lane holds row (qb + w*32 + c31), k = ks*16 + hi*8 .. +8
  const int qrow = qb + w * 32 + c31;
  const size_t qbase = ((size_t)(b * SEQ + qrow)) * EMB + h * HDIM + hi * 8;
  short8 bq_[4], bim[4];
  #pragma unroll
  for (int ks = 0; ks < 4; ++ks) {
    bq_[ks] = *(const short8*)&Qp [qbase + ks * 16];
    bim[ks] = *(const short8*)&Imb[qbase + ks * 16];
  }

  float lrA = 0.f, lrB = 0.f;      // per-lane softmax denominator (q = qrow), split chains
  f32x16 o0 = {}, o1 = {};         // PV accum, d-blocks 0/1

  const float SC = 0.03125f * 1.44269504089f;   // /sqrt(1024) * log2(e)
  const size_t kimBase = ((size_t)b * SEQ) * EMB + h * HDIM + gch * 8;
  const size_t vtBase  = ((size_t)bh * HDIM) * SEQ + gch * 8;

  // prologue: stage all of tile 0 (6 cp16 per wave = 24 total = 3 x 8 KB)
  #pragma unroll
  for (int s = 0; s < 6; ++s) {
    const int I = w * 6 + s;
    const int tz = I >> 3;
    const int row = ((I & 7) * 8) + lrow8;
    const short* g;
    if (tz == 0)      g = Kp  + kimBase + (size_t)row * EMB;
    else if (tz == 1) g = Imb + kimBase + (size_t)row * EMB;
    else              g = VtG + vtBase + (size_t)row * SEQ;
    cp16(g, &tiles[I * 512]);
  }
  __syncthreads();

  const int swz = c31 & 7;         // row-XOR (same for rows c31 and 32+c31)

  for (int kt = 0; kt < 16; ++kt) {
    const int kBaseN = (kt + 1) * 64;   // next tile base (unused when kt==15)

    // ---- QK phase (swapped): out row = k, col = q. A = K/Im rows from LDS, B = Q/Im regs.
    f32x16 s0 = {}, s1 = {};
    #pragma unroll
    for (int ks = 0; ks < 4; ++ks) {
      const int ch = ((ks * 2 + hi) ^ swz) * 8;
      const int r0off = c31 * 64 + ch, r1off = (32 + c31) * 64 + ch;
      short8 k0 = *(const short8*)&tiles[r0off];
      short8 k1 = *(const short8*)&tiles[r1off];
      short8 i0 = *(const short8*)&tiles[4096 + r0off];
      short8 i1 = *(const short8*)&tiles[4096 + r1off];
      s0 = __builtin_amdgcn_mfma_f32_32x32x16_bf16(k0, bq_[ks], s0, 0, 0, 0);
      s1 = __builtin_amdgcn_mfma_f32_32x32x16_bf16(k1, bq_[ks], s1, 0, 0, 0);
      s0 = __builtin_amdgcn_mfma_f32_32x32x16_bf16(i0, bim[ks], s0, 0, 0, 0);
      s1 = __builtin_amdgcn_mfma_f32_32x32x16_bf16(i1, bim[ks], s1, 0, 0, 0);
    }

    __syncthreads();   // BAR_A: all waves done reading K/Im(kt); Vt(kt) committed

    // ---- stage K/Im for kt+1 (4 cp16 per wave = 16 KB); commits at BAR_B
    if (kt != 15) {
      #pragma unroll
      for (int s = 0; s < 4; ++s) {
        const int I = w * 4 + s;            // 0..15
        const int row = ((I & 7) * 8) + lrow8;
        const short* g = ((I >> 3) ? Imb : Kp) + kimBase + (size_t)(kBaseN + row) * EMB;
        cp16(g, &tiles[I * 512]);
      }
    }

    // ---- exp, fully in-register. Lane L holds P[q=c31][k = (reg&3)+8*(reg>>2)+4*hi (+32 for s1)]
    float p0[16], p1[16];
    #pragma unroll
    for (int r = 0; r < 16; ++r) {
      p0[r] = __builtin_amdgcn_exp2f(s0[r] * SC);
      p1[r] = __builtin_amdgcn_exp2f(s1[r] * SC);
      lrA += p0[r];
      lrB += p1[r];
    }

    // ---- pack P -> PV A-frags via cvt_pk + permlane32_swap.
    // frag[ks] elems e: k = ks*16 + hi*8 + e. Pairs (p0,p1)&(p4,p5) -> words 0,2; (p2,p3)&(p6,p7) -> 1,3.
    short8 ap[4];
    #pragma unroll
    for (int half = 0; half < 2; ++half) {        // regs 0..7 / 8..15 -> ks = 2*kb + half
      {
        u32x2 sA = __builtin_amdgcn_permlane32_swap(
            cvt_pk_bf16(p0[half*8+0], p0[half*8+1]), cvt_pk_bf16(p0[half*8+4], p0[half*8+5]), false, false);
        u32x2 sB = __builtin_amdgcn_permlane32_swap(
            cvt_pk_bf16(p0[half*8+2], p0[half*8+3]), cvt_pk_bf16(p0[half*8+6], p0[half*8+7]), false, false);
        u32x4 wv = {sA[0], sB[0], sA[1], sB[1]};
        ap[half] = __builtin_bit_cast(short8, wv);
      }
      {
        u32x2 sA = __builtin_amdgcn_permlane32_swap(
            cvt_pk_bf16(p1[half*8+0], p1[half*8+1]), cvt_pk_bf16(p1[half*8+4], p1[half*8+5]), false, false);
        u32x2 sB = __builtin_amdgcn_permlane32_swap(
            cvt_pk_bf16(p1[half*8+2], p1[half*8+3]), cvt_pk_bf16(p1[half*8+6], p1[half*8+7]), false, false);
        u32x4 wv = {sA[0], sB[0], sA[1], sB[1]};
        ap[2 + half] = __builtin_bit_cast(short8, wv);
      }
    }

    // ---- PV phase: A = P frags, B = Vt rows (d = db*32 + c31) from LDS. out col = d, row = q.
    #pragma unroll
    for (int ks = 0; ks < 4; ++ks) {
      const int ch = ((ks * 2 + hi) ^ swz) * 8;
      short8 v0 = *(const short8*)&tiles[8192 + c31 * 64 + ch];
      short8 v1 = *(const short8*)&tiles[8192 + (32 + c31) * 64 + ch];
      o0 = __builtin_amdgcn_mfma_f32_32x32x16_bf16(ap[ks], v0, o0, 0, 0, 0);
      o1 = __builtin_amdgcn_mfma_f32_32x32x16_bf16(ap[ks], v1, o1, 0, 0, 0);
    }

    __syncthreads();   // BAR_B: all waves done reading Vt(kt); K/Im(kt+1) committed

    // ---- stage Vt for kt+1 (2 cp16 per wave = 8 KB); commits at next BAR_A
    if (kt != 15) {
      #pragma unroll
      for (int s = 0; s < 2; ++s) {
        const int I = 16 + w * 2 + s;       // 16..23
        const int row = ((I & 7) * 8) + lrow8;
        cp16(VtG + vtBase + (size_t)row * SEQ + kBaseN, &tiles[I * 512]);
      }
    }
  }

  // epilogue: lane pair (L, L+32) hold disjoint k-halves of q=c31's denominator
  float lr = lrA + lrB;
  lr += __shfl_xor(lr, 32);
  float inv = 1.f / lr;                  // valid for q-row (qb + w*32 + c31), all lanes

  // o[db][r] = O[q = qb+w*32+(r&3)+8*(r>>2)+4*hi][d = db*32 + c31]
  #pragma unroll
  for (int r = 0; r < 16; ++r) {
    const int qr = (r & 3) + 8 * (r >> 2) + 4 * hi;
    const float invr = __shfl(inv, qr);  // lane qr holds inv for q-row qb+w*32+qr
    const size_t base = ((size_t)(b * SEQ + qb + w * 32 + qr)) * EMB + h * HDIM + c31;
    attnA[base]      = (short)f2bf_fast(o0[r] * invr);
    attnA[base + 32] = (short)f2bf_fast(o1[r] * invr);
  }
}

// ---------------------------------------------------------------- launch
extern "C" void kernel_launch(void* const* d_in, const int* in_sizes, int n_in,
                              void* d_out, int out_size, void* d_ws, size_t ws_size,
                              hipStream_t stream) {
  const float* Re  = (const float*)d_in[0];
  const float* Im  = (const float*)d_in[1];
  const float* pos = (const float*)d_in[2];
  const float* Wq  = (const float*)d_in[3];
  const float* bq  = (const float*)d_in[4];
  const float* Wk  = (const float*)d_in[5];
  const float* bk  = (const float*)d_in[6];
  const float* Wv  = (const float*)d_in[7];
  const float* bv  = (const float*)d_in[8];
  const float* Wo  = (const float*)d_in[9];
  const float* bo  = (const float*)d_in[10];

  short* ws    = (short*)d_ws;
  short* Rebf  = ws;                         // 4M shorts
  short* Imbf  = ws + (size_t)MELEM;         // 4M
  short* Wt    = ws + (size_t)2 * MELEM;     // 4 x 1M (q,k,v,o)
  short* Qp    = ws + (size_t)3 * MELEM;     // Q,K projections + Vt: 3 x 4M
  short* Kp    = Qp + (size_t)MELEM;
  short* VtG   = Qp + (size_t)2 * MELEM;     // V transposed [b,h,d,s]
  short* attnA = ws + (size_t)6 * MELEM;     // 4M

  // fused convert + weight transpose (one launch)
  prep<<<dim3(12288), 256, 0, stream>>>(Re, Im, Rebf, Imbf, Wq, Wk, Wv, Wo, Wt);

  // fused Q/K/V projection (+bias +P), bf16 out; V written transposed. N fused to 3072.
  gemm_qkv<<<dim3(3 * EMB / 64, MTOT / 128), 256, 0, stream>>>(
      Rebf, Wt, bq, bk, bv, pos, Qp, VtG);

  // flash attention (x = bh for XCD-local L2 reuse of K/Im/Vt), 128-row q-tiles
  attn<<<dim3(BATCH * NHEAD, SEQ / 128), 256, 0, stream>>>(
      Qp, Kp, VtG, Imbf, attnA);

  // output projection, f32 out, 64x64 tiles, true pipeline
  gemm_wo<<<dim3(EMB / 64, MTOT / 64), 256, 0, stream>>>(
      attnA, Wt + 3 * EMB * EMB, bo, (float*)d_out);
}

// Round 6
// 190.195 us; speedup vs baseline: 1.1105x; 1.0022x over previous
//
#include <hip/hip_runtime.h>
#include <hip/hip_bf16.h>
#include <stdint.h>

// Problem constants
#define BATCH 4
#define SEQ   1024
#define EMB   1024
#define NHEAD 16
#define HDIM  64
#define MTOT  (BATCH*SEQ)          // 4096 rows
#define MELEM (MTOT*EMB)           // 4,194,304 elements per [B,S,E] tensor

typedef __attribute__((ext_vector_type(8))) short short8;
typedef __attribute__((ext_vector_type(4))) float f32x4;
typedef __attribute__((ext_vector_type(16))) float f32x16;
typedef __attribute__((ext_vector_type(4))) unsigned short us4;
typedef __attribute__((ext_vector_type(2))) unsigned int u32x2;
typedef __attribute__((ext_vector_type(4))) unsigned int u32x4;

// counted vmem wait (T4): NEVER drain to 0 inside a pipelined loop.
#define WAITV(N) asm volatile("s_waitcnt vmcnt(" #N ")" ::: "memory")
#define BARRIER() __builtin_amdgcn_s_barrier()

// fast f32->bf16: round-half-up via integer add (inputs finite, no NaN).
static __device__ __forceinline__ unsigned short f2bf_fast(float f) {
  unsigned u = __builtin_bit_cast(unsigned, f);
  return (unsigned short)((u + 0x8000u) >> 16);
}

// packed f32x2 -> bf16x2 (RNE), no builtin on gfx950 (T12/m240) -> inline asm
static __device__ __forceinline__ unsigned cvt_pk_bf16(float lo, float hi) {
  unsigned r;
  asm("v_cvt_pk_bf16_f32 %0, %1, %2" : "=v"(r) : "v"(lo), "v"(hi));
  return r;
}

// async global->LDS, 16B per lane. lds ptr must be WAVE-UNIFORM base;
// HW scatters lane i to base + i*16. (m97 recipe)
static __device__ __forceinline__ void cp16(const void* g, const void* lds_uniform) {
  __builtin_amdgcn_global_load_lds(
      (const __attribute__((address_space(1))) unsigned int*)(uintptr_t)g,
      (__attribute__((address_space(3))) unsigned int*)(unsigned int)(uintptr_t)lds_uniform,
      16, 0, 0);
}

// ---------------------------------------------------------------- prep: cvt f32->bf16 (Re,Im) + W transpose x4
// bid 0..4095: Re cvt | 4096..8191: Im cvt | 8192..12287: wtrans (z = (bid-8192)>>10)
__global__ __launch_bounds__(256) void prep(const float* __restrict__ Re,
                                            const float* __restrict__ Im,
                                            short* __restrict__ Rebf,
                                            short* __restrict__ Imbf,
                                            const float* __restrict__ W0,
                                            const float* __restrict__ W1,
                                            const float* __restrict__ W2,
                                            const float* __restrict__ W3,
                                            short* __restrict__ WtBase) {
  __shared__ short tile[32][33];
  const int bid = blockIdx.x;
  if (bid < 8192) {
    const float* in  = (bid >= 4096) ? Im   : Re;
    short*       out = (bid >= 4096) ? Imbf : Rebf;
    int i = (bid & 4095) * 256 + threadIdx.x;   // each thread: 4 elements
    float4 f = ((const float4*)in)[i];
    unsigned r0 = ((unsigned)f2bf_fast(f.y) << 16) | f2bf_fast(f.x);
    unsigned r1 = ((unsigned)f2bf_fast(f.w) << 16) | f2bf_fast(f.z);
    ((uint2*)out)[i] = make_uint2(r0, r1);
  } else {
    const int wb = bid - 8192;
    const int z = wb >> 10;
    const float* W = (z == 0) ? W0 : (z == 1) ? W1 : (z == 2) ? W2 : W3;
    short* Wt = WtBase + (size_t)z * EMB * EMB;
    const int rem = wb & 1023;
    const int nT = (rem & 31) * 32, kT = (rem >> 5) * 32;
    const int tx = threadIdx.x & 31, ty = threadIdx.x >> 5;   // 32 x 8
    #pragma unroll
    for (int i = 0; i < 4; ++i)
      tile[ty + 8*i][tx] = (short)f2bf_fast(W[(size_t)(kT + ty + 8*i) * EMB + nT + tx]);
    __syncthreads();
    #pragma unroll
    for (int i = 0; i < 4; ++i)
      Wt[(size_t)(nT + ty + 8*i) * EMB + kT + tx] = tile[tx][ty + 8*i];
  }
}

// ---------------------------------------------------------------- fused QKV GEMM, 128x128 tiles + T4 pipeline
// N fused to 3072. grid (24,32) = 768 blocks, 64 KB LDS -> 2 blocks/CU.
// R6: fat wave-tile (64x64, acc[4][4]) fixes the LDS read:MFMA ratio (8 b128 per
// 16 MFMA vs 12 per 16 at 128x64 — the measured critical resource), and the T4
// counted-vmcnt 2-deep prefetch replaces the inter-block TLP the fat tile forfeits
// (R1's 128x128 without the pipeline died of exposed latency at vmcnt(0) drains).
__global__ __launch_bounds__(256) void gemm_qkv(const short* __restrict__ A,
                                                const short* __restrict__ Wt,
                                                const float* __restrict__ bq,
                                                const float* __restrict__ bk,
                                                const float* __restrict__ bv,
                                                const float* __restrict__ pos,
                                                short* __restrict__ QKbase,
                                                short* __restrict__ vtOut) {
  const int m0 = blockIdx.y * 128, n0 = blockIdx.x * 128;
  const int z = n0 >> 10;                       // 0=Q 1=K 2=V (1024 % 128 == 0)
  const float* bias = (z == 0) ? bq : (z == 1 ? bk : bv);

  __shared__ __align__(16) short As[2][128 * 64];  // 2 x 16 KB
  __shared__ __align__(16) short Bs[2][128 * 64];  // 2 x 16 KB

  const int t = threadIdx.x;
  const int lane = t & 63, w = t >> 6;
  const int wm = w >> 1, wn = w & 1;            // wave tile 64m x 64n
  const int quad = lane >> 4, l16 = lane & 15;
  const int lrow8 = lane >> 3, lchunk = lane & 7;
  const int gch = lchunk ^ lrow8;               // swizzled source chunk
  const int sw7 = l16 & 7;

  const short* Arow = A  + (size_t)(m0 + w * 32 + lrow8) * EMB + gch * 8;
  const short* Brow = Wt + (size_t)(n0 + w * 32 + lrow8) * EMB + gch * 8;

  f32x4 acc[4][4] = {};

  auto STAGE = [&](short* as, short* bs, int k0) {   // 8 cp16 per thread
    #pragma unroll
    for (int s = 0; s < 4; ++s)
      cp16(Arow + (size_t)(s * 8) * EMB + k0, &as[(w * 32 + s * 8) * 64]);
    #pragma unroll
    for (int s = 0; s < 4; ++s)
      cp16(Brow + (size_t)(s * 8) * EMB + k0, &bs[(w * 32 + s * 8) * 64]);
  };
  auto COMPUTE = [&](const short* as, const short* bs) {
    #pragma unroll
    for (int ks = 0; ks < 2; ++ks) {
      const int chv = ((ks << 2) + quad) ^ sw7;
      short8 af[4], bfr[4];
      #pragma unroll
      for (int i = 0; i < 4; ++i)
        af[i] = *(const short8*)&as[(wm * 64 + i * 16 + l16) * 64 + chv * 8];
      #pragma unroll
      for (int j = 0; j < 4; ++j)
        bfr[j] = *(const short8*)&bs[(wn * 64 + j * 16 + l16) * 64 + chv * 8];
      #pragma unroll
      for (int i = 0; i < 4; ++i)
        #pragma unroll
        for (int j = 0; j < 4; ++j)
          acc[i][j] = __builtin_amdgcn_mfma_f32_16x16x32_bf16(af[i], bfr[j], acc[i][j], 0, 0, 0);
    }
  };

  STAGE(As[0], Bs[0], 0);      // tile 0 in flight
  STAGE(As[1], Bs[1], 64);     // tile 1 in flight (16 loads outstanding)

  #pragma unroll 1
  for (int p = 0; p < 7; ++p) {
    WAITV(8); BARRIER();                    // own tile-(2p) loads done; all waves synced
    COMPUTE(As[0], Bs[0]);                  // k = p*128
    BARRIER();                              // all waves done reading buf0
    STAGE(As[0], Bs[0], p * 128 + 128);     // tile 2p+2
    WAITV(8); BARRIER();
    COMPUTE(As[1], Bs[1]);                  // k = p*128 + 64
    BARRIER();
    STAGE(As[1], Bs[1], p * 128 + 192);     // tile 2p+3
  }
  WAITV(8); BARRIER();
  COMPUTE(As[0], Bs[0]);                    // k = 896
  BARRIER();
  WAITV(0); BARRIER();
  COMPUTE(As[1], Bs[1]);                    // k = 960

  // epilogue: C row = quad*4+r, col = l16  (verbatim from the harness-verified R1 kernel)
  #pragma unroll
  for (int i = 0; i < 4; ++i) {
    int mbase = m0 + wm * 64 + i * 16 + quad * 4;
    #pragma unroll
    for (int j = 0; j < 4; ++j) {
      int n = n0 + wn * 64 + j * 16 + l16;
      int nl = n & 1023;
      float bn = bias[nl];
      int d = nl & (HDIM - 1);
      if (z == 2) {
        // write V transposed: [b,h,d,s] so attn stages Vt rows contiguously
        int bh = (mbase >> 10) * NHEAD + (nl >> 6);
        int s = mbase & (SEQ - 1);
        us4 pk;
        #pragma unroll
        for (int r = 0; r < 4; ++r) {
          float v = acc[i][j][r] + bn + pos[(size_t)(mbase + r) * HDIM + d];
          pk[r] = f2bf_fast(v);
        }
        *(us4*)&vtOut[((size_t)bh * HDIM + d) * SEQ + s] = pk;
      } else {
        #pragma unroll
        for (int r = 0; r < 4; ++r) {
          int mm = mbase + r;
          float v = acc[i][j][r] + bn + pos[(size_t)mm * HDIM + d];
          QKbase[(size_t)z * MELEM + (size_t)mm * EMB + nl] = (short)f2bf_fast(v);
        }
      }
    }
  }
}

// ---------------------------------------------------------------- Wo GEMM: 64x64 tiles, true pipeline
// Counted-vmcnt (T4); STAGE = 4 cp16/thread -> WAITV(4). 32 KB LDS, 5 blocks/CU. (control)
__global__ __launch_bounds__(256) void gemm_wo(const short* __restrict__ A,
                                               const short* __restrict__ Bt,
                                               const float* __restrict__ bias,
                                               float* __restrict__ out) {
  const int m0 = blockIdx.y * 64, n0 = blockIdx.x * 64;

  __shared__ __align__(16) short As[2][64 * 64];
  __shared__ __align__(16) short Bs[2][64 * 64];

  const int t = threadIdx.x;
  const int lane = t & 63, w = t >> 6;
  const int wm = w >> 1, wn = w & 1;          // wave tile: 32m x 32n
  const int quad = lane >> 4, l16 = lane & 15;
  const int lrow8 = lane >> 3, lchunk = lane & 7;
  const int gch = lchunk ^ lrow8;
  const int sw7 = l16 & 7;

  const short* Arow = A  + (size_t)(m0 + w * 16 + lrow8) * EMB + gch * 8;
  const short* Brow = Bt + (size_t)(n0 + w * 16 + lrow8) * EMB + gch * 8;

  f32x4 acc[2][2] = {};

  auto STAGE = [&](short* as, short* bs, int k0) {   // 4 cp16 per thread
    #pragma unroll
    for (int s = 0; s < 2; ++s) {
      cp16(Arow + (size_t)(s * 8) * EMB + k0, &as[(w * 16 + s * 8) * 64]);
      cp16(Brow + (size_t)(s * 8) * EMB + k0, &bs[(w * 16 + s * 8) * 64]);
    }
  };
  auto COMPUTE = [&](const short* as, const short* bs) {
    #pragma unroll
    for (int ks = 0; ks < 2; ++ks) {
      const int chv = ((ks << 2) + quad) ^ sw7;
      short8 af[2], bfr[2];
      #pragma unroll
      for (int i = 0; i < 2; ++i)
        af[i] = *(const short8*)&as[(wm * 32 + i * 16 + l16) * 64 + chv * 8];
      #pragma unroll
      for (int j = 0; j < 2; ++j)
        bfr[j] = *(const short8*)&bs[(wn * 32 + j * 16 + l16) * 64 + chv * 8];
      #pragma unroll
      for (int i = 0; i < 2; ++i)
        #pragma unroll
        for (int j = 0; j < 2; ++j)
          acc[i][j] = __builtin_amdgcn_mfma_f32_16x16x32_bf16(af[i], bfr[j], acc[i][j], 0, 0, 0);
    }
  };

  STAGE(As[0], Bs[0], 0);
  STAGE(As[1], Bs[1], 64);

  #pragma unroll 1
  for (int p = 0; p < 7; ++p) {
    WAITV(4); BARRIER();
    COMPUTE(As[0], Bs[0]);
    BARRIER();
    STAGE(As[0], Bs[0], p * 128 + 128);
    WAITV(4); BARRIER();
    COMPUTE(As[1], Bs[1]);
    BARRIER();
    STAGE(As[1], Bs[1], p * 128 + 192);
  }
  WAITV(4); BARRIER();
  COMPUTE(As[0], Bs[0]);
  BARRIER();
  WAITV(0); BARRIER();
  COMPUTE(As[1], Bs[1]);

  #pragma unroll
  for (int i = 0; i < 2; ++i) {
    int mbase = m0 + wm * 32 + i * 16 + quad * 4;
    #pragma unroll
    for (int j = 0; j < 2; ++j) {
      int n = n0 + wn * 32 + j * 16 + l16;
      float bn = bias[n];
      #pragma unroll
      for (int r = 0; r < 4; ++r)
        out[(size_t)(mbase + r) * EMB + n] = acc[i][j][r] + bn;
    }
  }
}

// ---------------------------------------------------------------- flash attention v3: 32x32 MFMA,
// swapped QK^T, in-register P (T12). Per wave: 32 q-rows (B-operand cols), KVBLK=64.
//   QK: sa[kb] = mfma(K_rows, Q_cols) -> lane holds P[q=lane&31][32 k-values] IN REGISTERS.
//   softmax: per-lane scalar exp/accumulate (no LDS round-trip, no shuffles until epilogue).
//   P->A-frag: v_cvt_pk_bf16_f32 pairs + permlane32_swap (verified pairing vs m74/m101 C/D map).
//   PV: o[db] = mfma(P_frag, Vt_rows).
// Staging schedule & swizzles identical to the verified R2/R3 kernel (control this round):
//   QK(kt) -> BAR_A -> cp16 K/Im(kt+1) -> exp/pack -> PV(kt) -> BAR_B -> cp16 Vt(kt+1)
__global__ __launch_bounds__(256) void attn(const short* __restrict__ Qp,
                                            const short* __restrict__ Kp,
                                            const short* __restrict__ VtG,
                                            const short* __restrict__ Imb,
                                            short* __restrict__ attnA) {
  const int qb = blockIdx.y * 128;
  const int bh = blockIdx.x;
  const int b = bh >> 4, h = bh & 15;
  const int t = threadIdx.x, lane = t & 63, w = t >> 6;   // w: 0..3
  const int c31 = lane & 31;       // q-row (QK out col / PV A row) and d-row (PV out col)
  const int hi  = lane >> 5;       // half-wave: k-slice selector
  const int lrow8 = lane >> 3, lchunk = lane & 7;
  const int gch = lchunk ^ lrow8;  // staging swizzle: LDS[row][ch] = G[row][ch ^ (row&7)]

  __shared__ __align__(16) short tiles[3 * 64 * 64];   // K | Im | Vt  (24576 B)

  // Q/Im B-fragments in regs: lane holds row (qb + w*32 + c31), k = ks*16 + hi*8 .. +8
  const int qrow = qb + w * 32 + c31;
  const size_t qbase = ((size_t)(b * SEQ + qrow)) * EMB + h * HDIM + hi * 8;
  short8 bq_[4], bim[4];
  #pragma unroll
  for (int ks = 0; ks < 4; ++ks) {
    bq_[ks] = *(const short8*)&Qp [qbase + ks * 16];
    bim[ks] = *(const short8*)&Imb[qbase + ks * 16];
  }

  float lrA = 0.f, lrB = 0.f;      // per-lane softmax denominator (q = qrow), split chains
  f32x16 o0 = {}, o1 = {};         // PV accum, d-blocks 0/1

  const float SC = 0.03125f * 1.44269504089f;   // /sqrt(1024) * log2(e)
  const size_t kimBase = ((size_t)b * SEQ) * EMB + h * HDIM + gch * 8;
  const size_t vtBase  = ((size_t)bh * HDIM) * SEQ + gch * 8;

  // prologue: stage all of tile 0 (6 cp16 per wave = 24 total = 3 x 8 KB)
  #pragma unroll
  for (int s = 0; s < 6; ++s) {
    const int I = w * 6 + s;
    const int tz = I >> 3;
    const int row = ((I & 7) * 8) + lrow8;
    const short* g;
    if (tz == 0)      g = Kp  + kimBase + (size_t)row * EMB;
    else if (tz == 1) g = Imb + kimBase + (size_t)row * EMB;
    else              g = VtG + vtBase + (size_t)row * SEQ;
    cp16(g, &tiles[I * 512]);
  }
  __syncthreads();

  const int swz = c31 & 7;         // row-XOR (same for rows c31 and 32+c31)

  for (int kt = 0; kt < 16; ++kt) {
    const int kBaseN = (kt + 1) * 64;   // next tile base (unused when kt==15)

    // ---- QK phase (swapped): out row = k, col = q. A = K/Im rows from LDS, B = Q/Im regs.
    f32x16 s0 = {}, s1 = {};
    #pragma unroll
    for (int ks = 0; ks < 4; ++ks) {
      const int ch = ((ks * 2 + hi) ^ swz) * 8;
      const int r0off = c31 * 64 + ch, r1off = (32 + c31) * 64 + ch;
      short8 k0 = *(const short8*)&tiles[r0off];
      short8 k1 = *(const short8*)&tiles[r1off];
      short8 i0 = *(const short8*)&tiles[4096 + r0off];
      short8 i1 = *(const short8*)&tiles[4096 + r1off];
      s0 = __builtin_amdgcn_mfma_f32_32x32x16_bf16(k0, bq_[ks], s0, 0, 0, 0);
      s1 = __builtin_amdgcn_mfma_f32_32x32x16_bf16(k1, bq_[ks], s1, 0, 0, 0);
      s0 = __builtin_amdgcn_mfma_f32_32x32x16_bf16(i0, bim[ks], s0, 0, 0, 0);
      s1 = __builtin_amdgcn_mfma_f32_32x32x16_bf16(i1, bim[ks], s1, 0, 0, 0);
    }

    __syncthreads();   // BAR_A: all waves done reading K/Im(kt); Vt(kt) committed

    // ---- stage K/Im for kt+1 (4 cp16 per wave = 16 KB); commits at BAR_B
    if (kt != 15) {
      #pragma unroll
      for (int s = 0; s < 4; ++s) {
        const int I = w * 4 + s;            // 0..15
        const int row = ((I & 7) * 8) + lrow8;
        const short* g = ((I >> 3) ? Imb : Kp) + kimBase + (size_t)(kBaseN + row) * EMB;
        cp16(g, &tiles[I * 512]);
      }
    }

    // ---- exp, fully in-register. Lane L holds P[q=c31][k = (reg&3)+8*(reg>>2)+4*hi (+32 for s1)]
    float p0[16], p1[16];
    #pragma unroll
    for (int r = 0; r < 16; ++r) {
      p0[r] = __builtin_amdgcn_exp2f(s0[r] * SC);
      p1[r] = __builtin_amdgcn_exp2f(s1[r] * SC);
      lrA += p0[r];
      lrB += p1[r];
    }

    // ---- pack P -> PV A-frags via cvt_pk + permlane32_swap.
    // frag[ks] elems e: k = ks*16 + hi*8 + e. Pairs (p0,p1)&(p4,p5) -> words 0,2; (p2,p3)&(p6,p7) -> 1,3.
    short8 ap[4];
    #pragma unroll
    for (int half = 0; half < 2; ++half) {        // regs 0..7 / 8..15 -> ks = 2*kb + half
      {
        u32x2 sA = __builtin_amdgcn_permlane32_swap(
            cvt_pk_bf16(p0[half*8+0], p0[half*8+1]), cvt_pk_bf16(p0[half*8+4], p0[half*8+5]), false, false);
        u32x2 sB = __builtin_amdgcn_permlane32_swap(
            cvt_pk_bf16(p0[half*8+2], p0[half*8+3]), cvt_pk_bf16(p0[half*8+6], p0[half*8+7]), false, false);
        u32x4 wv = {sA[0], sB[0], sA[1], sB[1]};
        ap[half] = __builtin_bit_cast(short8, wv);
      }
      {
        u32x2 sA = __builtin_amdgcn_permlane32_swap(
            cvt_pk_bf16(p1[half*8+0], p1[half*8+1]), cvt_pk_bf16(p1[half*8+4], p1[half*8+5]), false, false);
        u32x2 sB = __builtin_amdgcn_permlane32_swap(
            cvt_pk_bf16(p1[half*8+2], p1[half*8+3]), cvt_pk_bf16(p1[half*8+6], p1[half*8+7]), false, false);
        u32x4 wv = {sA[0], sB[0], sA[1], sB[1]};
        ap[2 + half] = __builtin_bit_cast(short8, wv);
      }
    }

    // ---- PV phase: A = P frags, B = Vt rows (d = db*32 + c31) from LDS. out col = d, row = q.
    #pragma unroll
    for (int ks = 0; ks < 4; ++ks) {
      const int ch = ((ks * 2 + hi) ^ swz) * 8;
      short8 v0 = *(const short8*)&tiles[8192 + c31 * 64 + ch];
      short8 v1 = *(const short8*)&tiles[8192 + (32 + c31) * 64 + ch];
      o0 = __builtin_amdgcn_mfma_f32_32x32x16_bf16(ap[ks], v0, o0, 0, 0, 0);
      o1 = __builtin_amdgcn_mfma_f32_32x32x16_bf16(ap[ks], v1, o1, 0, 0, 0);
    }

    __syncthreads();   // BAR_B: all waves done reading Vt(kt); K/Im(kt+1) committed

    // ---- stage Vt for kt+1 (2 cp16 per wave = 8 KB); commits at next BAR_A
    if (kt != 15) {
      #pragma unroll
      for (int s = 0; s < 2; ++s) {
        const int I = 16 + w * 2 + s;       // 16..23
        const int row = ((I & 7) * 8) + lrow8;
        cp16(VtG + vtBase + (size_t)row * SEQ + kBaseN, &tiles[I * 512]);
      }
    }
  }

  // epilogue: lane pair (L, L+32) hold disjoint k-halves of q=c31's denominator
  float lr = lrA + lrB;
  lr += __shfl_xor(lr, 32);
  float inv = 1.f / lr;                  // valid for q-row (qb + w*32 + c31), all lanes

  // o[db][r] = O[q = qb+w*32+(r&3)+8*(r>>2)+4*hi][d = db*32 + c31]
  #pragma unroll
  for (int r = 0; r < 16; ++r) {
    const int qr = (r & 3) + 8 * (r >> 2) + 4 * hi;
    const float invr = __shfl(inv, qr);  // lane qr holds inv for q-row qb+w*32+qr
    const size_t base = ((size_t)(b * SEQ + qb + w * 32 + qr)) * EMB + h * HDIM + c31;
    attnA[base]      = (short)f2bf_fast(o0[r] * invr);
    attnA[base + 32] = (short)f2bf_fast(o1[r] * invr);
  }
}

// ---------------------------------------------------------------- launch
extern "C" void kernel_launch(void* const* d_in, const int* in_sizes, int n_in,
                              void* d_out, int out_size, void* d_ws, size_t ws_size,
                              hipStream_t stream) {
  const float* Re  = (const float*)d_in[0];
  const float* Im  = (const float*)d_in[1];
  const float* pos = (const float*)d_in[2];
  const float* Wq  = (const float*)d_in[3];
  const float* bq  = (const float*)d_in[4];
  const float* Wk  = (const float*)d_in[5];
  const float* bk  = (const float*)d_in[6];
  const float* Wv  = (const float*)d_in[7];
  const float* bv  = (const float*)d_in[8];
  const float* Wo  = (const float*)d_in[9];
  const float* bo  = (const float*)d_in[10];

  short* ws    = (short*)d_ws;
  short* Rebf  = ws;                         // 4M shorts
  short* Imbf  = ws + (size_t)MELEM;         // 4M
  short* Wt    = ws + (size_t)2 * MELEM;     // 4 x 1M (q,k,v,o)
  short* Qp    = ws + (size_t)3 * MELEM;     // Q,K projections + Vt: 3 x 4M
  short* Kp    = Qp + (size_t)MELEM;
  short* VtG   = Qp + (size_t)2 * MELEM;     // V transposed [b,h,d,s]
  short* attnA = ws + (size_t)6 * MELEM;     // 4M

  // fused convert + weight transpose (one launch)
  prep<<<dim3(12288), 256, 0, stream>>>(Re, Im, Rebf, Imbf, Wq, Wk, Wv, Wo, Wt);

  // fused Q/K/V projection (+bias +P), bf16 out; V written transposed. N fused to 3072.
  gemm_qkv<<<dim3(3 * EMB / 128, MTOT / 128), 256, 0, stream>>>(
      Rebf, Wt, bq, bk, bv, pos, Qp, VtG);

  // flash attention (x = bh for XCD-local L2 reuse of K/Im/Vt), 128-row q-tiles
  attn<<<dim3(BATCH * NHEAD, SEQ / 128), 256, 0, stream>>>(
      Qp, Kp, VtG, Imbf, attnA);

  // output projection, f32 out, 64x64 tiles, true pipeline
  gemm_wo<<<dim3(EMB / 64, MTOT / 64), 256, 0, stream>>>(
      attnA, Wt + 3 * EMB * EMB, bo, (float*)d_out);
}